// Round 2
// baseline (730.296 us; speedup 1.0000x reference)
//
#include <hip/hip_runtime.h>
#include <hip/hip_bf16.h>
#include <math.h>

#define N_ATOMS  50000
#define N_MOTIFS 50000
#define N_INC    600000
#define N_GRAPHS 512
#define H        64
#define MOTIF_DIM 94
#define HOUT     128
#define BN_EPS   1e-5f
#define TM       16   // rows per tile in the linear kernels

__device__ __forceinline__ float softplus_f(float x) {
    return fmaxf(x, 0.0f) + log1pf(expf(-fabsf(x)));
}
__device__ __forceinline__ float sigmoid_f(float x) {
    return 1.0f / (1.0f + expf(-x));
}

// x[i][j] = embed_table[atom_z[i]][j]
__global__ __launch_bounds__(256) void embed_kernel(const int* __restrict__ atom_z,
                                                    const float* __restrict__ table,
                                                    float* __restrict__ x) {
    int i = blockIdx.x * 4 + (threadIdx.x >> 6);
    if (i >= N_ATOMS) return;
    int j = threadIdx.x & 63;
    x[(size_t)i * H + j] = table[(size_t)atom_z[i] * H + j];
}

// degree histograms: cnt_m[hid]++, cnt_a[src]++
__global__ __launch_bounds__(256) void count_kernel(const int* __restrict__ he,
                                                    unsigned* __restrict__ cnt_m,
                                                    unsigned* __restrict__ cnt_a) {
    int e = blockIdx.x * 256 + threadIdx.x;
    if (e >= N_INC) return;
    atomicAdd(&cnt_m[he[N_INC + e]], 1u);
    atomicAdd(&cnt_a[he[e]], 1u);
}

// one block per side: exclusive prefix sum of 50000 counts -> base + cursor
__global__ __launch_bounds__(1024) void scan_kernel(const unsigned* __restrict__ cnt_m,
                                                    const unsigned* __restrict__ cnt_a,
                                                    unsigned* __restrict__ base_m,
                                                    unsigned* __restrict__ cur_m,
                                                    unsigned* __restrict__ base_a,
                                                    unsigned* __restrict__ cur_a) {
    const unsigned* cnt = blockIdx.x ? cnt_a : cnt_m;
    unsigned* base = blockIdx.x ? base_a : base_m;
    unsigned* cur  = blockIdx.x ? cur_a  : cur_m;
    __shared__ unsigned part[1024];
    int t = threadIdx.x;
    const int CH = 49;              // 1024*49 >= 50000
    int s0 = t * CH;
    unsigned local = 0;
    for (int i = 0; i < CH; i++) { int idx = s0 + i; if (idx < N_MOTIFS) local += cnt[idx]; }
    part[t] = local;
    __syncthreads();
    for (int off = 1; off < 1024; off <<= 1) {
        unsigned add = (t >= off) ? part[t - off] : 0u;
        __syncthreads();
        part[t] += add;
        __syncthreads();
    }
    unsigned run = (t > 0) ? part[t - 1] : 0u;
    for (int i = 0; i < CH; i++) {
        int idx = s0 + i;
        if (idx < N_MOTIFS) { base[idx] = run; cur[idx] = run; run += cnt[idx]; }
    }
}

// scatter edge endpoints into CSR slots
__global__ __launch_bounds__(256) void fill_kernel(const int* __restrict__ he,
                                                   unsigned* __restrict__ cur_m,
                                                   unsigned* __restrict__ cur_a,
                                                   int* __restrict__ csr_src,
                                                   int* __restrict__ csr_hid) {
    int e = blockIdx.x * 256 + threadIdx.x;
    if (e >= N_INC) return;
    int s = he[e];
    int h = he[N_INC + e];
    unsigned p = atomicAdd(&cur_m[h], 1u);
    csr_src[p] = s;
    unsigned q = atomicAdd(&cur_a[s], 1u);
    csr_hid[q] = h;
}

// a_f = x @ w_f[0:64,:], a_c = x @ w_c[0:64,:]   (bias folded into motif side)
__global__ __launch_bounds__(256) void atom_linear(const float* __restrict__ x,
                                                   const float* __restrict__ w_f,
                                                   const float* __restrict__ w_c,
                                                   float* __restrict__ a_f,
                                                   float* __restrict__ a_c) {
    __shared__ float z[TM][H];
    int m0 = blockIdx.x * TM;
    int tid = threadIdx.x;
    for (int idx = tid; idx < TM * H; idx += 256) {
        int m = idx >> 6, k = idx & 63;
        z[m][k] = x[(size_t)(m0 + m) * H + k];
    }
    __syncthreads();
    int j = tid & 127;
    int mset = tid >> 7;
    const float* w = (j < H) ? (w_f + j) : (w_c + (j - H));
    float acc[8];
#pragma unroll
    for (int i = 0; i < 8; i++) acc[i] = 0.0f;
    for (int k = 0; k < H; k++) {
        float wv = w[(size_t)k * H];
#pragma unroll
        for (int i = 0; i < 8; i++) acc[i] += z[mset * 8 + i][k] * wv;
    }
    float* dst = (j < H) ? a_f : a_c;
    int jj = j & 63;
#pragma unroll
    for (int i = 0; i < 8; i++) {
        int m = m0 + mset * 8 + i;
        dst[(size_t)m * H + jj] = acc[i];
    }
}

// one wave per motif: hx_mean[m] = mean over incident atoms of x[src]
__global__ __launch_bounds__(256) void hx_gather(const unsigned* __restrict__ base_m,
                                                 const unsigned* __restrict__ cnt_m,
                                                 const int* __restrict__ csr_src,
                                                 const float* __restrict__ x,
                                                 float* __restrict__ hx_mean) {
    int m = blockIdx.x * 4 + (threadIdx.x >> 6);
    int j = threadIdx.x & 63;
    unsigned b = base_m[m];
    unsigned d = cnt_m[m];
    float acc = 0.0f;
    unsigned k = 0;
    for (; k + 4 <= d; k += 4) {
        int s0 = csr_src[b + k], s1 = csr_src[b + k + 1];
        int s2 = csr_src[b + k + 2], s3 = csr_src[b + k + 3];
        acc += x[(size_t)s0 * H + j] + x[(size_t)s1 * H + j]
             + x[(size_t)s2 * H + j] + x[(size_t)s3 * H + j];
    }
    for (; k < d; k++) acc += x[(size_t)csr_src[b + k] * H + j];
    hx_mean[(size_t)m * H + j] = acc / fmaxf((float)d, 1.0f);
}

// m_f = [hx_mean | motif_attr] @ w_{f}[64:222,:] + b_f   (and same for c)
__global__ __launch_bounds__(256) void motif_linear(const float* __restrict__ hx_mean,
                                                    const float* __restrict__ motif_attr,
                                                    const float* __restrict__ w_f,
                                                    const float* __restrict__ b_f,
                                                    const float* __restrict__ w_c,
                                                    const float* __restrict__ b_c,
                                                    float* __restrict__ m_f,
                                                    float* __restrict__ m_c) {
    __shared__ float z[TM][160];   // 158 used, pad to 160
    int m0 = blockIdx.x * TM;
    int tid = threadIdx.x;
    for (int idx = tid; idx < TM * H; idx += 256) {
        int m = idx >> 6, k = idx & 63;
        z[m][k] = hx_mean[(size_t)(m0 + m) * H + k];
    }
    for (int idx = tid; idx < TM * MOTIF_DIM; idx += 256) {
        int m = idx / MOTIF_DIM, k = idx % MOTIF_DIM;
        z[m][H + k] = motif_attr[(size_t)(m0 + m) * MOTIF_DIM + k];
    }
    __syncthreads();
    int j = tid & 127;
    int mset = tid >> 7;
    const float* w = (j < H) ? (w_f + (size_t)H * H + j) : (w_c + (size_t)H * H + (j - H));
    float bias = (j < H) ? b_f[j] : b_c[j - H];
    float acc[8];
#pragma unroll
    for (int i = 0; i < 8; i++) acc[i] = bias;
    for (int k = 0; k < H + MOTIF_DIM; k++) {
        float wv = w[(size_t)k * H];
#pragma unroll
        for (int i = 0; i < 8; i++) acc[i] += z[mset * 8 + i][k] * wv;
    }
    float* dst = (j < H) ? m_f : m_c;
    int jj = j & 63;
#pragma unroll
    for (int i = 0; i < 8; i++) {
        int m = m0 + mset * 8 + i;
        dst[(size_t)m * H + jj] = acc[i];
    }
}

// one wave per atom: out_mean[i] = mean over incident motifs of gated message
__global__ __launch_bounds__(256) void msg_gather(const unsigned* __restrict__ base_a,
                                                  const unsigned* __restrict__ cnt_a,
                                                  const int* __restrict__ csr_hid,
                                                  const float* __restrict__ a_f,
                                                  const float* __restrict__ a_c,
                                                  const float* __restrict__ m_f,
                                                  const float* __restrict__ m_c,
                                                  float* __restrict__ out_mean) {
    int i = blockIdx.x * 4 + (threadIdx.x >> 6);
    int j = threadIdx.x & 63;
    float af = a_f[(size_t)i * H + j];
    float ac = a_c[(size_t)i * H + j];
    unsigned b = base_a[i];
    unsigned d = cnt_a[i];
    float acc = 0.0f;
    unsigned k = 0;
    for (; k + 2 <= d; k += 2) {
        int h0 = csr_hid[b + k], h1 = csr_hid[b + k + 1];
        float f0 = af + m_f[(size_t)h0 * H + j];
        float c0 = ac + m_c[(size_t)h0 * H + j];
        float f1 = af + m_f[(size_t)h1 * H + j];
        float c1 = ac + m_c[(size_t)h1 * H + j];
        acc += sigmoid_f(f0) * softplus_f(c0) + sigmoid_f(f1) * softplus_f(c1);
    }
    for (; k < d; k++) {
        int h0 = csr_hid[b + k];
        acc += sigmoid_f(af + m_f[(size_t)h0 * H + j]) * softplus_f(ac + m_c[(size_t)h0 * H + j]);
    }
    out_mean[(size_t)i * H + j] = acc / fmaxf((float)d, 1.0f);
}

// column-wise sum and sumsq of out_mean over atoms
__global__ __launch_bounds__(256) void bn_stats(const float* __restrict__ out_mean,
                                                float* __restrict__ bn_sum,
                                                float* __restrict__ bn_sq) {
    __shared__ float ssum[256];
    __shared__ float ssq[256];
    int j = threadIdx.x & 63;
    int row = threadIdx.x >> 6;
    float s = 0.0f, q = 0.0f;
    for (int i = blockIdx.x * 4 + row; i < N_ATOMS; i += gridDim.x * 4) {
        float v = out_mean[(size_t)i * H + j];
        s += v; q += v * v;
    }
    ssum[threadIdx.x] = s; ssq[threadIdx.x] = q;
    __syncthreads();
    if (threadIdx.x < 64) {
        float ts = ssum[j] + ssum[64 + j] + ssum[128 + j] + ssum[192 + j];
        float tq = ssq[j] + ssq[64 + j] + ssq[128 + j] + ssq[192 + j];
        atomicAdd(&bn_sum[j], ts);
        atomicAdd(&bn_sq[j], tq);
    }
}

// BN (training stats) + residual + relu, then scatter-add into per-graph pool
__global__ __launch_bounds__(256) void bn_apply_pool(const float* __restrict__ out_mean,
                                                     const float* __restrict__ bn_sum,
                                                     const float* __restrict__ bn_sq,
                                                     const float* __restrict__ gamma,
                                                     const float* __restrict__ beta,
                                                     const float* __restrict__ x,
                                                     const int* __restrict__ batch,
                                                     float* __restrict__ g_sum,
                                                     unsigned* __restrict__ g_cnt) {
    int i = blockIdx.x * 4 + (threadIdx.x >> 6);
    if (i >= N_ATOMS) return;
    int j = threadIdx.x & 63;
    const float invN = 1.0f / (float)N_ATOMS;
    float mu = bn_sum[j] * invN;
    float var = bn_sq[j] * invN - mu * mu;
    float rstd = 1.0f / sqrtf(var + BN_EPS);
    float d = out_mean[(size_t)i * H + j];
    float o = (d - mu) * rstd * gamma[j] + beta[j];
    float xr = fmaxf(o + x[(size_t)i * H + j], 0.0f);
    int b = batch[i];
    atomicAdd(&g_sum[(size_t)b * H + j], xr);
    if (j == 0) atomicAdd(&g_cnt[b], 1u);
}

// per-graph: gv = g_sum/cnt; h = softplus(gv@w_l1+b_l1); out = h@w_out + b_out
__global__ __launch_bounds__(128) void head_kernel(const float* __restrict__ g_sum,
                                                   const unsigned* __restrict__ g_cnt,
                                                   const float* __restrict__ w_l1,
                                                   const float* __restrict__ b_l1,
                                                   const float* __restrict__ w_out,
                                                   const float* __restrict__ b_out,
                                                   float* __restrict__ out) {
    __shared__ float gv[H];
    __shared__ float red[HOUT];
    int g = blockIdx.x, t = threadIdx.x;
    if (t < H) gv[t] = g_sum[(size_t)g * H + t] / fmaxf((float)g_cnt[g], 1.0f);
    __syncthreads();
    float acc = b_l1[t];
    for (int k = 0; k < H; k++) acc += gv[k] * w_l1[(size_t)k * HOUT + t];
    float h = softplus_f(acc);
    red[t] = h * w_out[t];
    __syncthreads();
    for (int s = 64; s > 0; s >>= 1) {
        if (t < s) red[t] += red[t + s];
        __syncthreads();
    }
    if (t == 0) out[g] = red[0] + b_out[0];
}

extern "C" void kernel_launch(void* const* d_in, const int* in_sizes, int n_in,
                              void* d_out, int out_size, void* d_ws, size_t ws_size,
                              hipStream_t stream) {
    const int*   atom_z     = (const int*)  d_in[0];
    const float* motif_attr = (const float*)d_in[1];
    const int*   he         = (const int*)  d_in[2];
    const int*   batch      = (const int*)  d_in[3];
    const float* table      = (const float*)d_in[4];
    const float* w_f        = (const float*)d_in[5];
    const float* b_f        = (const float*)d_in[6];
    const float* w_c        = (const float*)d_in[7];
    const float* b_c        = (const float*)d_in[8];
    const float* gamma      = (const float*)d_in[9];
    const float* beta       = (const float*)d_in[10];
    const float* w_l1       = (const float*)d_in[11];
    const float* b_l1       = (const float*)d_in[12];
    const float* w_out      = (const float*)d_in[13];
    const float* b_out      = (const float*)d_in[14];
    float* out = (float*)d_out;

    // ---- workspace layout ----
    // zeroed region first:
    unsigned* cnt_m  = (unsigned*)d_ws;                 // 50,000
    unsigned* cnt_a  = cnt_m + N_MOTIFS;                // 50,000
    float*    bn_sum = (float*)(cnt_a + N_ATOMS);       // 64
    float*    bn_sq  = bn_sum + H;                      // 64
    float*    g_sum  = bn_sq + H;                       // 32,768
    unsigned* g_cnt  = (unsigned*)(g_sum + (size_t)N_GRAPHS * H); // 512
    char*     zero_end = (char*)(g_cnt + N_GRAPHS);
    // un-zeroed:
    unsigned* base_m = (unsigned*)zero_end;             // 50,000
    unsigned* cur_m  = base_m + N_MOTIFS;               // 50,000
    unsigned* base_a = cur_m + N_MOTIFS;                // 50,000
    unsigned* cur_a  = base_a + N_ATOMS;                // 50,000
    int*      csr_src = (int*)(cur_a + N_ATOMS);        // 600,000
    int*      csr_hid = csr_src + N_INC;                // 600,000
    float*    x       = (float*)(csr_hid + N_INC);      // 3.2M
    float*    a_f     = x   + (size_t)N_ATOMS * H;
    float*    a_c     = a_f + (size_t)N_ATOMS * H;
    float*    m_f     = a_c + (size_t)N_ATOMS * H;
    float*    m_c     = m_f + (size_t)N_MOTIFS * H;
    float*    hx_mean = m_c + (size_t)N_MOTIFS * H;     // aliased: also out_mean
    float*    out_mean = hx_mean;  // hx_mean dead after motif_linear

    size_t zero_bytes = (size_t)(zero_end - (char*)d_ws);
    hipMemsetAsync(d_ws, 0, zero_bytes, stream);

    embed_kernel<<<N_ATOMS / 4, 256, 0, stream>>>(atom_z, table, x);
    count_kernel<<<(N_INC + 255) / 256, 256, 0, stream>>>(he, cnt_m, cnt_a);
    scan_kernel<<<2, 1024, 0, stream>>>(cnt_m, cnt_a, base_m, cur_m, base_a, cur_a);
    fill_kernel<<<(N_INC + 255) / 256, 256, 0, stream>>>(he, cur_m, cur_a, csr_src, csr_hid);
    atom_linear<<<N_ATOMS / TM, 256, 0, stream>>>(x, w_f, w_c, a_f, a_c);
    hx_gather<<<N_MOTIFS / 4, 256, 0, stream>>>(base_m, cnt_m, csr_src, x, hx_mean);
    motif_linear<<<N_MOTIFS / TM, 256, 0, stream>>>(hx_mean, motif_attr,
                                                    w_f, b_f, w_c, b_c, m_f, m_c);
    msg_gather<<<N_ATOMS / 4, 256, 0, stream>>>(base_a, cnt_a, csr_hid,
                                                a_f, a_c, m_f, m_c, out_mean);
    bn_stats<<<1024, 256, 0, stream>>>(out_mean, bn_sum, bn_sq);
    bn_apply_pool<<<N_ATOMS / 4, 256, 0, stream>>>(out_mean, bn_sum, bn_sq,
                                                   gamma, beta, x, batch, g_sum, g_cnt);
    head_kernel<<<N_GRAPHS, 128, 0, stream>>>(g_sum, g_cnt, w_l1, b_l1, w_out, b_out, out);
}

// Round 3
// 484.130 us; speedup vs baseline: 1.5085x; 1.5085x over previous
//
#include <hip/hip_runtime.h>
#include <hip/hip_bf16.h>
#include <math.h>

#define N_ATOMS  50000
#define N_MOTIFS 50000
#define N_SEG    (N_MOTIFS + N_ATOMS)   // 100000 combined segments
#define N_INC    600000
#define N_GRAPHS 512
#define H        64
#define MOTIF_DIM 94
#define HOUT     128
#define BN_EPS   1e-5f
#define TM       16
#define NZ       101
#define SCAN_NBLK 98                    // ceil(100000/1024)

__device__ __forceinline__ float softplus_fast(float x) {
    // max(x,0) + log(1+exp(-|x|)) with HW exp2/log2
    return fmaxf(x, 0.0f) + __logf(1.0f + __expf(-fabsf(x)));
}
__device__ __forceinline__ float gate_f(float f, float c) {
    float sig = __builtin_amdgcn_rcpf(1.0f + __expf(-f));
    return sig * softplus_fast(c);
}

// degree histogram over combined segment space: [0,50k)=motifs, [50k,100k)=atoms
__global__ __launch_bounds__(256) void count_kernel(const int* __restrict__ he,
                                                    unsigned* __restrict__ cnt) {
    int e = blockIdx.x * 256 + threadIdx.x;
    if (e >= N_INC) return;
    atomicAdd(&cnt[he[N_INC + e]], 1u);            // motif side
    atomicAdd(&cnt[N_MOTIFS + he[e]], 1u);         // atom side
}

// phase 1: per-block (1024 elems) sums
__global__ __launch_bounds__(256) void scan_part(const unsigned* __restrict__ cnt,
                                                 unsigned* __restrict__ part) {
    __shared__ unsigned red[256];
    int b = blockIdx.x, t = threadIdx.x;
    int i0 = b * 1024 + t * 4;
    unsigned s = 0;
#pragma unroll
    for (int i = 0; i < 4; i++) { int idx = i0 + i; if (idx < N_SEG) s += cnt[idx]; }
    red[t] = s;
    __syncthreads();
    for (int off = 128; off > 0; off >>= 1) {
        if (t < off) red[t] += red[t + off];
        __syncthreads();
    }
    if (t == 0) part[b] = red[0];
}

// phase 2: exclusive scan of 98 block sums (one block)
__global__ __launch_bounds__(128) void scan_top(const unsigned* __restrict__ part,
                                                unsigned* __restrict__ part_pre) {
    __shared__ unsigned s[128];
    int t = threadIdx.x;
    s[t] = (t < SCAN_NBLK) ? part[t] : 0u;
    __syncthreads();
    for (int off = 1; off < 128; off <<= 1) {
        unsigned add = (t >= off) ? s[t - off] : 0u;
        __syncthreads();
        s[t] += add;
        __syncthreads();
    }
    if (t < SCAN_NBLK) part_pre[t] = (t > 0) ? s[t - 1] : 0u;
}

// phase 3: block-local exclusive scan + global offset -> base, cur
__global__ __launch_bounds__(256) void scan_down(const unsigned* __restrict__ cnt,
                                                 const unsigned* __restrict__ part_pre,
                                                 unsigned* __restrict__ base,
                                                 unsigned* __restrict__ cur) {
    __shared__ unsigned s[256];
    int b = blockIdx.x, t = threadIdx.x;
    int i0 = b * 1024 + t * 4;
    unsigned c[4];
#pragma unroll
    for (int i = 0; i < 4; i++) { int idx = i0 + i; c[i] = (idx < N_SEG) ? cnt[idx] : 0u; }
    s[t] = c[0] + c[1] + c[2] + c[3];
    __syncthreads();
    for (int off = 1; off < 256; off <<= 1) {
        unsigned add = (t >= off) ? s[t - off] : 0u;
        __syncthreads();
        s[t] += add;
        __syncthreads();
    }
    unsigned pre = part_pre[b] + ((t > 0) ? s[t - 1] : 0u);
#pragma unroll
    for (int i = 0; i < 4; i++) {
        int idx = i0 + i;
        if (idx < N_SEG) { base[idx] = pre; cur[idx] = pre; pre += c[i]; }
    }
}

// CSR fill: motif side stores the atom's TYPE (z), atom side stores motif id
__global__ __launch_bounds__(256) void fill_kernel(const int* __restrict__ he,
                                                   const int* __restrict__ atom_z,
                                                   unsigned* __restrict__ cur,
                                                   int* __restrict__ csr_val) {
    int e = blockIdx.x * 256 + threadIdx.x;
    if (e >= N_INC) return;
    int s = he[e];
    int h = he[N_INC + e];
    unsigned p = atomicAdd(&cur[h], 1u);
    csr_val[p] = atom_z[s];
    unsigned q = atomicAdd(&cur[N_MOTIFS + s], 1u);
    csr_val[q] = h;
}

// fused embed + atom-side projection: x[i]=table[z[i]]; a_fc[i][j]=(x@wf, x@wc) interleaved
__global__ __launch_bounds__(256) void atom_linear(const int* __restrict__ atom_z,
                                                   const float* __restrict__ table,
                                                   const float* __restrict__ w_f,
                                                   const float* __restrict__ w_c,
                                                   float* __restrict__ x,
                                                   float* __restrict__ a_fc) {
    __shared__ float z[TM][H];
    int m0 = blockIdx.x * TM;
    int tid = threadIdx.x;
    for (int idx = tid; idx < TM * H; idx += 256) {
        int m = idx >> 6, k = idx & 63;
        float v = table[(size_t)atom_z[m0 + m] * H + k];
        z[m][k] = v;
        x[(size_t)(m0 + m) * H + k] = v;
    }
    __syncthreads();
    int j = tid & 127;
    int mset = tid >> 7;
    const float* w = (j < H) ? (w_f + j) : (w_c + (j - H));
    float acc[8];
#pragma unroll
    for (int i = 0; i < 8; i++) acc[i] = 0.0f;
    for (int k = 0; k < H; k++) {
        float wv = w[(size_t)k * H];
#pragma unroll
        for (int i = 0; i < 8; i++) acc[i] += z[mset * 8 + i][k] * wv;
    }
    int jj = j & 63;
    int sel = (j < H) ? 0 : 1;
#pragma unroll
    for (int i = 0; i < 8; i++) {
        int m = m0 + mset * 8 + i;
        a_fc[(((size_t)m * H + jj) << 1) + sel] = acc[i];
    }
}

// hx_mean from LDS-resident embed table; CSR holds atom types directly
#define MPB 16
__global__ __launch_bounds__(256) void hx_gather(const unsigned* __restrict__ base,
                                                 const unsigned* __restrict__ cnt,
                                                 const int* __restrict__ csr_val,
                                                 const float* __restrict__ table,
                                                 float* __restrict__ hx_mean) {
    __shared__ float tab[NZ * H];
    int tid = threadIdx.x;
    for (int idx = tid; idx < NZ * H; idx += 256) tab[idx] = table[idx];
    __syncthreads();
    int wave = tid >> 6, j = tid & 63;
    for (int w = 0; w < MPB / 4; w++) {
        int m = blockIdx.x * MPB + wave * (MPB / 4) + w;
        unsigned b = base[m];
        unsigned d = cnt[m];
        float acc = 0.0f;
        unsigned k = 0;
        for (; k + 4 <= d; k += 4) {
            int z0 = csr_val[b + k],     z1 = csr_val[b + k + 1];
            int z2 = csr_val[b + k + 2], z3 = csr_val[b + k + 3];
            acc += tab[z0 * H + j] + tab[z1 * H + j] + tab[z2 * H + j] + tab[z3 * H + j];
        }
        for (; k < d; k++) acc += tab[csr_val[b + k] * H + j];
        hx_mean[(size_t)m * H + j] = acc / fmaxf((float)d, 1.0f);
    }
}

// m_fc = proj of [hx_mean | motif_attr] through rows 64:222 of w_f/w_c (+bias), interleaved
__global__ __launch_bounds__(256) void motif_linear(const float* __restrict__ hx_mean,
                                                    const float* __restrict__ motif_attr,
                                                    const float* __restrict__ w_f,
                                                    const float* __restrict__ b_f,
                                                    const float* __restrict__ w_c,
                                                    const float* __restrict__ b_c,
                                                    float* __restrict__ m_fc) {
    __shared__ float z[TM][160];
    int m0 = blockIdx.x * TM;
    int tid = threadIdx.x;
    for (int idx = tid; idx < TM * H; idx += 256) {
        int m = idx >> 6, k = idx & 63;
        z[m][k] = hx_mean[(size_t)(m0 + m) * H + k];
    }
    for (int idx = tid; idx < TM * MOTIF_DIM; idx += 256) {
        int m = idx / MOTIF_DIM, k = idx % MOTIF_DIM;
        z[m][H + k] = motif_attr[(size_t)(m0 + m) * MOTIF_DIM + k];
    }
    __syncthreads();
    int j = tid & 127;
    int mset = tid >> 7;
    const float* w = (j < H) ? (w_f + (size_t)H * H + j) : (w_c + (size_t)H * H + (j - H));
    float bias = (j < H) ? b_f[j] : b_c[j - H];
    float acc[8];
#pragma unroll
    for (int i = 0; i < 8; i++) acc[i] = bias;
    for (int k = 0; k < H + MOTIF_DIM; k++) {
        float wv = w[(size_t)k * H];
#pragma unroll
        for (int i = 0; i < 8; i++) acc[i] += z[mset * 8 + i][k] * wv;
    }
    int jj = j & 63;
    int sel = (j < H) ? 0 : 1;
#pragma unroll
    for (int i = 0; i < 8; i++) {
        int m = m0 + mset * 8 + i;
        m_fc[(((size_t)m * H + jj) << 1) + sel] = acc[i];
    }
}

// one wave per atom: out_mean[i] = mean_h gate(a_fc[i] + m_fc[h]); float2 = one 512B wave load/edge
__global__ __launch_bounds__(256) void msg_gather(const unsigned* __restrict__ base,
                                                  const unsigned* __restrict__ cnt,
                                                  const int* __restrict__ csr_val,
                                                  const float2* __restrict__ a_fc,
                                                  const float2* __restrict__ m_fc,
                                                  float* __restrict__ out_mean) {
    int i = blockIdx.x * 4 + (threadIdx.x >> 6);
    int j = threadIdx.x & 63;
    float2 a = a_fc[(size_t)i * H + j];
    unsigned b = base[N_MOTIFS + i];
    unsigned d = cnt[N_MOTIFS + i];
    float acc = 0.0f;
    unsigned k = 0;
    for (; k + 4 <= d; k += 4) {
        int h0 = csr_val[b + k],     h1 = csr_val[b + k + 1];
        int h2 = csr_val[b + k + 2], h3 = csr_val[b + k + 3];
        float2 v0 = m_fc[(size_t)h0 * H + j];
        float2 v1 = m_fc[(size_t)h1 * H + j];
        float2 v2 = m_fc[(size_t)h2 * H + j];
        float2 v3 = m_fc[(size_t)h3 * H + j];
        acc += gate_f(a.x + v0.x, a.y + v0.y) + gate_f(a.x + v1.x, a.y + v1.y)
             + gate_f(a.x + v2.x, a.y + v2.y) + gate_f(a.x + v3.x, a.y + v3.y);
    }
    for (; k < d; k++) {
        int h0 = csr_val[b + k];
        float2 v0 = m_fc[(size_t)h0 * H + j];
        acc += gate_f(a.x + v0.x, a.y + v0.y);
    }
    out_mean[(size_t)i * H + j] = acc / fmaxf((float)d, 1.0f);
}

// column-wise sum and sumsq of out_mean over atoms
__global__ __launch_bounds__(256) void bn_stats(const float* __restrict__ out_mean,
                                                float* __restrict__ bn_sum,
                                                float* __restrict__ bn_sq) {
    __shared__ float ssum[256];
    __shared__ float ssq[256];
    int j = threadIdx.x & 63;
    int row = threadIdx.x >> 6;
    float s = 0.0f, q = 0.0f;
    for (int i = blockIdx.x * 4 + row; i < N_ATOMS; i += gridDim.x * 4) {
        float v = out_mean[(size_t)i * H + j];
        s += v; q += v * v;
    }
    ssum[threadIdx.x] = s; ssq[threadIdx.x] = q;
    __syncthreads();
    if (threadIdx.x < 64) {
        float ts = ssum[j] + ssum[64 + j] + ssum[128 + j] + ssum[192 + j];
        float tq = ssq[j] + ssq[64 + j] + ssq[128 + j] + ssq[192 + j];
        atomicAdd(&bn_sum[j], ts);
        atomicAdd(&bn_sq[j], tq);
    }
}

// BN + residual + relu, scatter-add into per-graph pool
__global__ __launch_bounds__(256) void bn_apply_pool(const float* __restrict__ out_mean,
                                                     const float* __restrict__ bn_sum,
                                                     const float* __restrict__ bn_sq,
                                                     const float* __restrict__ gamma,
                                                     const float* __restrict__ beta,
                                                     const float* __restrict__ x,
                                                     const int* __restrict__ batch,
                                                     float* __restrict__ g_sum,
                                                     unsigned* __restrict__ g_cnt) {
    int i = blockIdx.x * 4 + (threadIdx.x >> 6);
    if (i >= N_ATOMS) return;
    int j = threadIdx.x & 63;
    const float invN = 1.0f / (float)N_ATOMS;
    float mu = bn_sum[j] * invN;
    float var = bn_sq[j] * invN - mu * mu;
    float rstd = 1.0f / sqrtf(var + BN_EPS);
    float d = out_mean[(size_t)i * H + j];
    float o = (d - mu) * rstd * gamma[j] + beta[j];
    float xr = fmaxf(o + x[(size_t)i * H + j], 0.0f);
    int b = batch[i];
    atomicAdd(&g_sum[(size_t)b * H + j], xr);
    if (j == 0) atomicAdd(&g_cnt[b], 1u);
}

// per-graph MLP head
__global__ __launch_bounds__(128) void head_kernel(const float* __restrict__ g_sum,
                                                   const unsigned* __restrict__ g_cnt,
                                                   const float* __restrict__ w_l1,
                                                   const float* __restrict__ b_l1,
                                                   const float* __restrict__ w_out,
                                                   const float* __restrict__ b_out,
                                                   float* __restrict__ out) {
    __shared__ float gv[H];
    __shared__ float red[HOUT];
    int g = blockIdx.x, t = threadIdx.x;
    if (t < H) gv[t] = g_sum[(size_t)g * H + t] / fmaxf((float)g_cnt[g], 1.0f);
    __syncthreads();
    float acc = b_l1[t];
    for (int k = 0; k < H; k++) acc += gv[k] * w_l1[(size_t)k * HOUT + t];
    float h = softplus_fast(acc);
    red[t] = h * w_out[t];
    __syncthreads();
    for (int s = 64; s > 0; s >>= 1) {
        if (t < s) red[t] += red[t + s];
        __syncthreads();
    }
    if (t == 0) out[g] = red[0] + b_out[0];
}

extern "C" void kernel_launch(void* const* d_in, const int* in_sizes, int n_in,
                              void* d_out, int out_size, void* d_ws, size_t ws_size,
                              hipStream_t stream) {
    const int*   atom_z     = (const int*)  d_in[0];
    const float* motif_attr = (const float*)d_in[1];
    const int*   he         = (const int*)  d_in[2];
    const int*   batch      = (const int*)  d_in[3];
    const float* table      = (const float*)d_in[4];
    const float* w_f        = (const float*)d_in[5];
    const float* b_f        = (const float*)d_in[6];
    const float* w_c        = (const float*)d_in[7];
    const float* b_c        = (const float*)d_in[8];
    const float* gamma      = (const float*)d_in[9];
    const float* beta       = (const float*)d_in[10];
    const float* w_l1       = (const float*)d_in[11];
    const float* b_l1       = (const float*)d_in[12];
    const float* w_out      = (const float*)d_in[13];
    const float* b_out      = (const float*)d_in[14];
    float* out = (float*)d_out;

    // ---- workspace layout ----
    // zeroed region:
    unsigned* cnt    = (unsigned*)d_ws;                    // 100,000
    float*    bn_sum = (float*)(cnt + N_SEG);              // 64
    float*    bn_sq  = bn_sum + H;                         // 64
    float*    g_sum  = bn_sq + H;                          // 32,768
    unsigned* g_cnt  = (unsigned*)(g_sum + (size_t)N_GRAPHS * H); // 512
    char*     zero_end = (char*)(g_cnt + N_GRAPHS);
    // un-zeroed region:
    unsigned* base     = (unsigned*)zero_end;              // 100,000
    unsigned* cur      = base + N_SEG;                     // 100,000
    unsigned* part     = cur + N_SEG;                      // 128
    unsigned* part_pre = part + 128;                       // 128
    int*      csr_val  = (int*)(part_pre + 128);           // 1,200,000
    float*    x        = (float*)(csr_val + 2 * N_INC);    // 3.2M
    float*    a_fc     = x + (size_t)N_ATOMS * H;          // 6.4M (f/c interleaved)
    float*    m_fc     = a_fc + (size_t)N_ATOMS * H * 2;   // 6.4M (f/c interleaved)
    float*    hx_mean  = m_fc + (size_t)N_MOTIFS * H * 2;  // 3.2M
    float*    out_mean = hx_mean;                          // alias: hx dead after motif_linear

    size_t zero_bytes = (size_t)(zero_end - (char*)d_ws);
    hipMemsetAsync(d_ws, 0, zero_bytes, stream);

    count_kernel<<<(N_INC + 255) / 256, 256, 0, stream>>>(he, cnt);
    scan_part<<<SCAN_NBLK, 256, 0, stream>>>(cnt, part);
    scan_top<<<1, 128, 0, stream>>>(part, part_pre);
    scan_down<<<SCAN_NBLK, 256, 0, stream>>>(cnt, part_pre, base, cur);
    fill_kernel<<<(N_INC + 255) / 256, 256, 0, stream>>>(he, atom_z, cur, csr_val);
    atom_linear<<<N_ATOMS / TM, 256, 0, stream>>>(atom_z, table, w_f, w_c, x, a_fc);
    hx_gather<<<N_MOTIFS / MPB, 256, 0, stream>>>(base, cnt, csr_val, table, hx_mean);
    motif_linear<<<N_MOTIFS / TM, 256, 0, stream>>>(hx_mean, motif_attr,
                                                    w_f, b_f, w_c, b_c, m_fc);
    msg_gather<<<N_ATOMS / 4, 256, 0, stream>>>(base, cnt, csr_val,
                                                (const float2*)a_fc, (const float2*)m_fc,
                                                out_mean);
    bn_stats<<<1024, 256, 0, stream>>>(out_mean, bn_sum, bn_sq);
    bn_apply_pool<<<N_ATOMS / 4, 256, 0, stream>>>(out_mean, bn_sum, bn_sq,
                                                   gamma, beta, x, batch, g_sum, g_cnt);
    head_kernel<<<N_GRAPHS, 128, 0, stream>>>(g_sum, g_cnt, w_l1, b_l1, w_out, b_out, out);
}

// Round 4
// 467.092 us; speedup vs baseline: 1.5635x; 1.0365x over previous
//
#include <hip/hip_runtime.h>
#include <hip/hip_bf16.h>
#include <math.h>

#define N_ATOMS  50000
#define N_MOTIFS 50000
#define N_SEG    (N_MOTIFS + N_ATOMS)   // 100000 combined segments
#define N_INC    600000
#define N_GRAPHS 512
#define H        64
#define MOTIF_DIM 94
#define HOUT     128
#define BN_EPS   1e-5f
#define NZ       101
#define SCAN_NBLK 98                    // ceil(100000/1024)
#define TL       64                     // rows per block in the linear kernels
#define NBLK_L   ((N_ATOMS + TL - 1) / TL)   // 782

__device__ __forceinline__ float softplus_fast(float x) {
    return fmaxf(x, 0.0f) + __logf(1.0f + __expf(-fabsf(x)));
}
__device__ __forceinline__ float gate_f(float f, float c) {
    float sig = __builtin_amdgcn_rcpf(1.0f + __expf(-f));
    return sig * softplus_fast(c);
}

// degree histogram over combined segment space: [0,50k)=motifs, [50k,100k)=atoms
__global__ __launch_bounds__(256) void count_kernel(const int* __restrict__ he,
                                                    unsigned* __restrict__ cnt) {
    int e = blockIdx.x * 256 + threadIdx.x;
    if (e >= N_INC) return;
    atomicAdd(&cnt[he[N_INC + e]], 1u);
    atomicAdd(&cnt[N_MOTIFS + he[e]], 1u);
}

// phase 1: per-block (1024 elems) sums
__global__ __launch_bounds__(256) void scan_part(const unsigned* __restrict__ cnt,
                                                 unsigned* __restrict__ part) {
    __shared__ unsigned red[256];
    int b = blockIdx.x, t = threadIdx.x;
    int i0 = b * 1024 + t * 4;
    unsigned s = 0;
#pragma unroll
    for (int i = 0; i < 4; i++) { int idx = i0 + i; if (idx < N_SEG) s += cnt[idx]; }
    red[t] = s;
    __syncthreads();
    for (int off = 128; off > 0; off >>= 1) {
        if (t < off) red[t] += red[t + off];
        __syncthreads();
    }
    if (t == 0) part[b] = red[0];
}

// phase 2: exclusive scan of 98 block sums
__global__ __launch_bounds__(128) void scan_top(const unsigned* __restrict__ part,
                                                unsigned* __restrict__ part_pre) {
    __shared__ unsigned s[128];
    int t = threadIdx.x;
    s[t] = (t < SCAN_NBLK) ? part[t] : 0u;
    __syncthreads();
    for (int off = 1; off < 128; off <<= 1) {
        unsigned add = (t >= off) ? s[t - off] : 0u;
        __syncthreads();
        s[t] += add;
        __syncthreads();
    }
    if (t < SCAN_NBLK) part_pre[t] = (t > 0) ? s[t - 1] : 0u;
}

// phase 3: block-local exclusive scan + global offset -> base, cur
__global__ __launch_bounds__(256) void scan_down(const unsigned* __restrict__ cnt,
                                                 const unsigned* __restrict__ part_pre,
                                                 unsigned* __restrict__ base,
                                                 unsigned* __restrict__ cur) {
    __shared__ unsigned s[256];
    int b = blockIdx.x, t = threadIdx.x;
    int i0 = b * 1024 + t * 4;
    unsigned c[4];
#pragma unroll
    for (int i = 0; i < 4; i++) { int idx = i0 + i; c[i] = (idx < N_SEG) ? cnt[idx] : 0u; }
    s[t] = c[0] + c[1] + c[2] + c[3];
    __syncthreads();
    for (int off = 1; off < 256; off <<= 1) {
        unsigned add = (t >= off) ? s[t - off] : 0u;
        __syncthreads();
        s[t] += add;
        __syncthreads();
    }
    unsigned pre = part_pre[b] + ((t > 0) ? s[t - 1] : 0u);
#pragma unroll
    for (int i = 0; i < 4; i++) {
        int idx = i0 + i;
        if (idx < N_SEG) { base[idx] = pre; cur[idx] = pre; pre += c[i]; }
    }
}

// XCD-partitioned CSR fill: class = blockIdx%8 (round-robin -> XCD). A class only
// writes CSR slots of segment groups ((id>>4)&7)==class, so each 64B line of
// csr_val is dirtied from ~one XCD's L2 (kills cross-XCD partial-line writebacks).
__global__ __launch_bounds__(256) void fill_kernel(const int* __restrict__ he,
                                                   const int* __restrict__ atom_z,
                                                   unsigned* __restrict__ cur,
                                                   int* __restrict__ csr_val) {
    int cls = blockIdx.x & 7;
    int bi  = blockIdx.x >> 3;
    int nb  = gridDim.x >> 3;
    for (int e = bi * 256 + threadIdx.x; e < N_INC; e += nb * 256) {
        int s = he[e];
        int h = he[N_INC + e];
        if (((h >> 4) & 7) == cls) {
            unsigned p = atomicAdd(&cur[h], 1u);
            csr_val[p] = atom_z[s];
        }
        if (((s >> 4) & 7) == cls) {
            unsigned q = atomicAdd(&cur[N_MOTIFS + s], 1u);
            csr_val[q] = h;
        }
    }
}

// fused embed + atom projection, register-blocked 8 rows x 4 cols per thread
__global__ __launch_bounds__(256) void atom_linear(const int* __restrict__ atom_z,
                                                   const float* __restrict__ table,
                                                   const float* __restrict__ w_f,
                                                   const float* __restrict__ w_c,
                                                   float* __restrict__ x,
                                                   float* __restrict__ a_fc) {
    __shared__ float z[TL][H];
    __shared__ int zz[TL];
    int m0 = blockIdx.x * TL;
    int tid = threadIdx.x;
    if (tid < TL) {
        int gm = m0 + tid;
        zz[tid] = (gm < N_ATOMS) ? atom_z[gm] : 0;
    }
    __syncthreads();
    for (int idx = tid; idx < TL * 16; idx += 256) {
        int m = idx >> 4, k4 = idx & 15;
        float4 v = ((const float4*)table)[(size_t)zz[m] * 16 + k4];
        *(float4*)&z[m][k4 * 4] = v;
        int gm = m0 + m;
        if (gm < N_ATOMS) ((float4*)x)[(size_t)gm * 16 + k4] = v;
    }
    __syncthreads();
    int rg = tid >> 5;          // 8 row groups of 8
    int cg = tid & 31;          // 32 col groups of 4 (128 outputs: f then c)
    int c0 = cg * 4;
    int sel = (c0 >= 64) ? 1 : 0;
    int jj = c0 & 63;
    const float* wsrc = (sel ? w_c : w_f) + jj;
    float acc[8][4];
#pragma unroll
    for (int i = 0; i < 8; i++)
#pragma unroll
        for (int c = 0; c < 4; c++) acc[i][c] = 0.0f;
    for (int k = 0; k < H; k += 2) {
        float4 w0 = *(const float4*)(wsrc + (size_t)k * H);
        float4 w1 = *(const float4*)(wsrc + (size_t)(k + 1) * H);
        float2 zv[8];
#pragma unroll
        for (int i = 0; i < 8; i++) zv[i] = *(const float2*)&z[rg * 8 + i][k];
#pragma unroll
        for (int i = 0; i < 8; i++) {
            acc[i][0] += zv[i].x * w0.x + zv[i].y * w1.x;
            acc[i][1] += zv[i].x * w0.y + zv[i].y * w1.y;
            acc[i][2] += zv[i].x * w0.z + zv[i].y * w1.z;
            acc[i][3] += zv[i].x * w0.w + zv[i].y * w1.w;
        }
    }
#pragma unroll
    for (int i = 0; i < 8; i++) {
        int gm = m0 + rg * 8 + i;
        if (gm < N_ATOMS) {
#pragma unroll
            for (int c = 0; c < 4; c++)
                a_fc[(((size_t)gm * H + (jj + c)) << 1) + sel] = acc[i][c];
        }
    }
}

// hx_mean from LDS-resident embed table; CSR motif side holds atom types
#define MPB 16
__global__ __launch_bounds__(256) void hx_gather(const unsigned* __restrict__ base,
                                                 const unsigned* __restrict__ cnt,
                                                 const int* __restrict__ csr_val,
                                                 const float* __restrict__ table,
                                                 float* __restrict__ hx_mean) {
    __shared__ float tab[NZ * H];
    int tid = threadIdx.x;
    for (int idx = tid; idx < NZ * H; idx += 256) tab[idx] = table[idx];
    __syncthreads();
    int wave = tid >> 6, j = tid & 63;
    for (int w = 0; w < MPB / 4; w++) {
        int m = blockIdx.x * MPB + wave * (MPB / 4) + w;
        unsigned b = base[m];
        unsigned d = cnt[m];
        float acc = 0.0f;
        unsigned k = 0;
        for (; k + 4 <= d; k += 4) {
            int z0 = csr_val[b + k],     z1 = csr_val[b + k + 1];
            int z2 = csr_val[b + k + 2], z3 = csr_val[b + k + 3];
            acc += tab[z0 * H + j] + tab[z1 * H + j] + tab[z2 * H + j] + tab[z3 * H + j];
        }
        for (; k < d; k++) acc += tab[csr_val[b + k] * H + j];
        hx_mean[(size_t)m * H + j] = acc / fmaxf((float)d, 1.0f);
    }
}

// motif projection (K=158, rows 64:222 of w_f/w_c, +bias), register-blocked 8x4
__global__ __launch_bounds__(256) void motif_linear(const float* __restrict__ hx_mean,
                                                    const float* __restrict__ motif_attr,
                                                    const float* __restrict__ w_f,
                                                    const float* __restrict__ b_f,
                                                    const float* __restrict__ w_c,
                                                    const float* __restrict__ b_c,
                                                    float* __restrict__ m_fc) {
    __shared__ float z[TL][160];   // 158 used
    int m0 = blockIdx.x * TL;
    int tid = threadIdx.x;
    for (int idx = tid; idx < TL * 16; idx += 256) {
        int m = idx >> 4, k4 = idx & 15;
        int gm = m0 + m;
        float4 v = make_float4(0.f, 0.f, 0.f, 0.f);
        if (gm < N_MOTIFS) v = ((const float4*)hx_mean)[(size_t)gm * 16 + k4];
        *(float4*)&z[m][k4 * 4] = v;
    }
    for (int idx = tid; idx < TL * 47; idx += 256) {
        int m = idx / 47, k2 = idx % 47;
        int gm = m0 + m;
        float2 v = make_float2(0.f, 0.f);
        if (gm < N_MOTIFS) v = ((const float2*)motif_attr)[(size_t)gm * 47 + k2];
        *(float2*)&z[m][H + k2 * 2] = v;
    }
    __syncthreads();
    int rg = tid >> 5;
    int cg = tid & 31;
    int c0 = cg * 4;
    int sel = (c0 >= 64) ? 1 : 0;
    int jj = c0 & 63;
    const float* wsrc = (sel ? w_c : w_f) + (size_t)H * H + jj;
    float4 bias = *(const float4*)((sel ? b_c : b_f) + jj);
    float acc[8][4];
#pragma unroll
    for (int i = 0; i < 8; i++) {
        acc[i][0] = bias.x; acc[i][1] = bias.y; acc[i][2] = bias.z; acc[i][3] = bias.w;
    }
    for (int k = 0; k < H + MOTIF_DIM; k += 2) {
        float4 w0 = *(const float4*)(wsrc + (size_t)k * H);
        float4 w1 = *(const float4*)(wsrc + (size_t)(k + 1) * H);
        float2 zv[8];
#pragma unroll
        for (int i = 0; i < 8; i++) zv[i] = *(const float2*)&z[rg * 8 + i][k];
#pragma unroll
        for (int i = 0; i < 8; i++) {
            acc[i][0] += zv[i].x * w0.x + zv[i].y * w1.x;
            acc[i][1] += zv[i].x * w0.y + zv[i].y * w1.y;
            acc[i][2] += zv[i].x * w0.z + zv[i].y * w1.z;
            acc[i][3] += zv[i].x * w0.w + zv[i].y * w1.w;
        }
    }
#pragma unroll
    for (int i = 0; i < 8; i++) {
        int gm = m0 + rg * 8 + i;
        if (gm < N_MOTIFS) {
#pragma unroll
            for (int c = 0; c < 4; c++)
                m_fc[(((size_t)gm * H + (jj + c)) << 1) + sel] = acc[i][c];
        }
    }
}

// one wave per atom: out_mean[i] = mean_h gate(a_fc[i] + m_fc[h])
__global__ __launch_bounds__(256) void msg_gather(const unsigned* __restrict__ base,
                                                  const unsigned* __restrict__ cnt,
                                                  const int* __restrict__ csr_val,
                                                  const float2* __restrict__ a_fc,
                                                  const float2* __restrict__ m_fc,
                                                  float* __restrict__ out_mean) {
    int i = blockIdx.x * 4 + (threadIdx.x >> 6);
    int j = threadIdx.x & 63;
    float2 a = a_fc[(size_t)i * H + j];
    unsigned b = base[N_MOTIFS + i];
    unsigned d = cnt[N_MOTIFS + i];
    float acc = 0.0f;
    unsigned k = 0;
    for (; k + 4 <= d; k += 4) {
        int h0 = csr_val[b + k],     h1 = csr_val[b + k + 1];
        int h2 = csr_val[b + k + 2], h3 = csr_val[b + k + 3];
        float2 v0 = m_fc[(size_t)h0 * H + j];
        float2 v1 = m_fc[(size_t)h1 * H + j];
        float2 v2 = m_fc[(size_t)h2 * H + j];
        float2 v3 = m_fc[(size_t)h3 * H + j];
        acc += gate_f(a.x + v0.x, a.y + v0.y) + gate_f(a.x + v1.x, a.y + v1.y)
             + gate_f(a.x + v2.x, a.y + v2.y) + gate_f(a.x + v3.x, a.y + v3.y);
    }
    for (; k < d; k++) {
        int h0 = csr_val[b + k];
        float2 v0 = m_fc[(size_t)h0 * H + j];
        acc += gate_f(a.x + v0.x, a.y + v0.y);
    }
    out_mean[(size_t)i * H + j] = acc / fmaxf((float)d, 1.0f);
}

// column-wise sum and sumsq of out_mean over atoms
__global__ __launch_bounds__(256) void bn_stats(const float* __restrict__ out_mean,
                                                float* __restrict__ bn_sum,
                                                float* __restrict__ bn_sq) {
    __shared__ float ssum[256];
    __shared__ float ssq[256];
    int j = threadIdx.x & 63;
    int row = threadIdx.x >> 6;
    float s = 0.0f, q = 0.0f;
    for (int i = blockIdx.x * 4 + row; i < N_ATOMS; i += gridDim.x * 4) {
        float v = out_mean[(size_t)i * H + j];
        s += v; q += v * v;
    }
    ssum[threadIdx.x] = s; ssq[threadIdx.x] = q;
    __syncthreads();
    if (threadIdx.x < 64) {
        float ts = ssum[j] + ssum[64 + j] + ssum[128 + j] + ssum[192 + j];
        float tq = ssq[j] + ssq[64 + j] + ssq[128 + j] + ssq[192 + j];
        atomicAdd(&bn_sum[j], ts);
        atomicAdd(&bn_sq[j], tq);
    }
}

// BN + residual + relu, scatter-add into per-graph pool
__global__ __launch_bounds__(256) void bn_apply_pool(const float* __restrict__ out_mean,
                                                     const float* __restrict__ bn_sum,
                                                     const float* __restrict__ bn_sq,
                                                     const float* __restrict__ gamma,
                                                     const float* __restrict__ beta,
                                                     const float* __restrict__ x,
                                                     const int* __restrict__ batch,
                                                     float* __restrict__ g_sum,
                                                     unsigned* __restrict__ g_cnt) {
    int i = blockIdx.x * 4 + (threadIdx.x >> 6);
    if (i >= N_ATOMS) return;
    int j = threadIdx.x & 63;
    const float invN = 1.0f / (float)N_ATOMS;
    float mu = bn_sum[j] * invN;
    float var = bn_sq[j] * invN - mu * mu;
    float rstd = 1.0f / sqrtf(var + BN_EPS);
    float d = out_mean[(size_t)i * H + j];
    float o = (d - mu) * rstd * gamma[j] + beta[j];
    float xr = fmaxf(o + x[(size_t)i * H + j], 0.0f);
    int b = batch[i];
    atomicAdd(&g_sum[(size_t)b * H + j], xr);
    if (j == 0) atomicAdd(&g_cnt[b], 1u);
}

// per-graph MLP head
__global__ __launch_bounds__(128) void head_kernel(const float* __restrict__ g_sum,
                                                   const unsigned* __restrict__ g_cnt,
                                                   const float* __restrict__ w_l1,
                                                   const float* __restrict__ b_l1,
                                                   const float* __restrict__ w_out,
                                                   const float* __restrict__ b_out,
                                                   float* __restrict__ out) {
    __shared__ float gv[H];
    __shared__ float red[HOUT];
    int g = blockIdx.x, t = threadIdx.x;
    if (t < H) gv[t] = g_sum[(size_t)g * H + t] / fmaxf((float)g_cnt[g], 1.0f);
    __syncthreads();
    float acc = b_l1[t];
    for (int k = 0; k < H; k++) acc += gv[k] * w_l1[(size_t)k * HOUT + t];
    float h = softplus_fast(acc);
    red[t] = h * w_out[t];
    __syncthreads();
    for (int s = 64; s > 0; s >>= 1) {
        if (t < s) red[t] += red[t + s];
        __syncthreads();
    }
    if (t == 0) out[g] = red[0] + b_out[0];
}

extern "C" void kernel_launch(void* const* d_in, const int* in_sizes, int n_in,
                              void* d_out, int out_size, void* d_ws, size_t ws_size,
                              hipStream_t stream) {
    const int*   atom_z     = (const int*)  d_in[0];
    const float* motif_attr = (const float*)d_in[1];
    const int*   he         = (const int*)  d_in[2];
    const int*   batch      = (const int*)  d_in[3];
    const float* table      = (const float*)d_in[4];
    const float* w_f        = (const float*)d_in[5];
    const float* b_f        = (const float*)d_in[6];
    const float* w_c        = (const float*)d_in[7];
    const float* b_c        = (const float*)d_in[8];
    const float* gamma      = (const float*)d_in[9];
    const float* beta       = (const float*)d_in[10];
    const float* w_l1       = (const float*)d_in[11];
    const float* b_l1       = (const float*)d_in[12];
    const float* w_out      = (const float*)d_in[13];
    const float* b_out      = (const float*)d_in[14];
    float* out = (float*)d_out;

    // ---- workspace layout ----
    unsigned* cnt    = (unsigned*)d_ws;                    // 100,000 (zeroed)
    float*    bn_sum = (float*)(cnt + N_SEG);              // 64
    float*    bn_sq  = bn_sum + H;                         // 64
    float*    g_sum  = bn_sq + H;                          // 32,768
    unsigned* g_cnt  = (unsigned*)(g_sum + (size_t)N_GRAPHS * H); // 512
    char*     zero_end = (char*)(g_cnt + N_GRAPHS);
    unsigned* base     = (unsigned*)zero_end;              // 100,000
    unsigned* cur      = base + N_SEG;                     // 100,000
    unsigned* part     = cur + N_SEG;                      // 128
    unsigned* part_pre = part + 128;                       // 128
    int*      csr_val  = (int*)(part_pre + 128);           // 1,200,000
    float*    x        = (float*)(csr_val + 2 * N_INC);    // 3.2M
    float*    a_fc     = x + (size_t)N_ATOMS * H;          // 6.4M interleaved
    float*    m_fc     = a_fc + (size_t)N_ATOMS * H * 2;   // 6.4M interleaved
    float*    hx_mean  = m_fc + (size_t)N_MOTIFS * H * 2;  // 3.2M
    float*    out_mean = hx_mean;                          // alias

    size_t zero_bytes = (size_t)(zero_end - (char*)d_ws);
    hipMemsetAsync(d_ws, 0, zero_bytes, stream);

    count_kernel<<<(N_INC + 255) / 256, 256, 0, stream>>>(he, cnt);
    scan_part<<<SCAN_NBLK, 256, 0, stream>>>(cnt, part);
    scan_top<<<1, 128, 0, stream>>>(part, part_pre);
    scan_down<<<SCAN_NBLK, 256, 0, stream>>>(cnt, part_pre, base, cur);
    fill_kernel<<<512, 256, 0, stream>>>(he, atom_z, cur, csr_val);
    atom_linear<<<NBLK_L, 256, 0, stream>>>(atom_z, table, w_f, w_c, x, a_fc);
    hx_gather<<<N_MOTIFS / MPB, 256, 0, stream>>>(base, cnt, csr_val, table, hx_mean);
    motif_linear<<<NBLK_L, 256, 0, stream>>>(hx_mean, motif_attr,
                                             w_f, b_f, w_c, b_c, m_fc);
    msg_gather<<<N_ATOMS / 4, 256, 0, stream>>>(base, cnt, csr_val,
                                                (const float2*)a_fc, (const float2*)m_fc,
                                                out_mean);
    bn_stats<<<1024, 256, 0, stream>>>(out_mean, bn_sum, bn_sq);
    bn_apply_pool<<<N_ATOMS / 4, 256, 0, stream>>>(out_mean, bn_sum, bn_sq,
                                                   gamma, beta, x, batch, g_sum, g_cnt);
    head_kernel<<<N_GRAPHS, 128, 0, stream>>>(g_sum, g_cnt, w_l1, b_l1, w_out, b_out, out);
}

// Round 5
// 424.614 us; speedup vs baseline: 1.7199x; 1.1000x over previous
//
#include <hip/hip_runtime.h>
#include <hip/hip_bf16.h>
#include <math.h>

#define N_ATOMS  50000
#define N_MOTIFS 50000
#define N_SEG    (N_MOTIFS + N_ATOMS)   // 100000 combined segments
#define N_INC    600000
#define N_GRAPHS 512
#define H        64
#define MOTIF_DIM 94
#define HOUT     128
#define BN_EPS   1e-5f
#define NZ       101
#define SCAN_NBLK 98                    // ceil(100000/1024)
#define TL       64                     // rows per block in the linear kernels
#define NBLK_L   ((N_ATOMS + TL - 1) / TL)   // 782

__device__ __forceinline__ float softplus_fast(float x) {
    return fmaxf(x, 0.0f) + __logf(1.0f + __expf(-fabsf(x)));
}
__device__ __forceinline__ float gate_f(float f, float c) {
    float sig = __builtin_amdgcn_rcpf(1.0f + __expf(-f));
    return sig * softplus_fast(c);
}

// degree histogram over combined segment space: [0,50k)=motifs, [50k,100k)=atoms
__global__ __launch_bounds__(256) void count_kernel(const int* __restrict__ he,
                                                    unsigned* __restrict__ cnt) {
    int e = blockIdx.x * 256 + threadIdx.x;
    if (e >= N_INC) return;
    atomicAdd(&cnt[he[N_INC + e]], 1u);
    atomicAdd(&cnt[N_MOTIFS + he[e]], 1u);
}

// phase 1: per-block (1024 elems) sums
__global__ __launch_bounds__(256) void scan_part(const unsigned* __restrict__ cnt,
                                                 unsigned* __restrict__ part) {
    __shared__ unsigned red[256];
    int b = blockIdx.x, t = threadIdx.x;
    int i0 = b * 1024 + t * 4;
    unsigned s = 0;
#pragma unroll
    for (int i = 0; i < 4; i++) { int idx = i0 + i; if (idx < N_SEG) s += cnt[idx]; }
    red[t] = s;
    __syncthreads();
    for (int off = 128; off > 0; off >>= 1) {
        if (t < off) red[t] += red[t + off];
        __syncthreads();
    }
    if (t == 0) part[b] = red[0];
}

// phase 2: exclusive scan of 98 block sums
__global__ __launch_bounds__(128) void scan_top(const unsigned* __restrict__ part,
                                                unsigned* __restrict__ part_pre) {
    __shared__ unsigned s[128];
    int t = threadIdx.x;
    s[t] = (t < SCAN_NBLK) ? part[t] : 0u;
    __syncthreads();
    for (int off = 1; off < 128; off <<= 1) {
        unsigned add = (t >= off) ? s[t - off] : 0u;
        __syncthreads();
        s[t] += add;
        __syncthreads();
    }
    if (t < SCAN_NBLK) part_pre[t] = (t > 0) ? s[t - 1] : 0u;
}

// phase 3: block-local exclusive scan + global offset -> base, cur
__global__ __launch_bounds__(256) void scan_down(const unsigned* __restrict__ cnt,
                                                 const unsigned* __restrict__ part_pre,
                                                 unsigned* __restrict__ base,
                                                 unsigned* __restrict__ cur) {
    __shared__ unsigned s[256];
    int b = blockIdx.x, t = threadIdx.x;
    int i0 = b * 1024 + t * 4;
    unsigned c[4];
#pragma unroll
    for (int i = 0; i < 4; i++) { int idx = i0 + i; c[i] = (idx < N_SEG) ? cnt[idx] : 0u; }
    s[t] = c[0] + c[1] + c[2] + c[3];
    __syncthreads();
    for (int off = 1; off < 256; off <<= 1) {
        unsigned add = (t >= off) ? s[t - off] : 0u;
        __syncthreads();
        s[t] += add;
        __syncthreads();
    }
    unsigned pre = part_pre[b] + ((t > 0) ? s[t - 1] : 0u);
#pragma unroll
    for (int i = 0; i < 4; i++) {
        int idx = i0 + i;
        if (idx < N_SEG) { base[idx] = pre; cur[idx] = pre; pre += c[i]; }
    }
}

// XCD-partitioned CSR fill (class = blockIdx%8 -> XCD; writes only its segment groups)
__global__ __launch_bounds__(256) void fill_kernel(const int* __restrict__ he,
                                                   const int* __restrict__ atom_z,
                                                   unsigned* __restrict__ cur,
                                                   int* __restrict__ csr_val) {
    int cls = blockIdx.x & 7;
    int bi  = blockIdx.x >> 3;
    int nb  = gridDim.x >> 3;
    for (int e = bi * 256 + threadIdx.x; e < N_INC; e += nb * 256) {
        int s = he[e];
        int h = he[N_INC + e];
        if (((h >> 4) & 7) == cls) {
            unsigned p = atomicAdd(&cur[h], 1u);
            csr_val[p] = atom_z[s];
        }
        if (((s >> 4) & 7) == cls) {
            unsigned q = atomicAdd(&cur[N_MOTIFS + s], 1u);
            csr_val[q] = h;
        }
    }
}

// embed (from table, LDS-staged) + atom projection, register-blocked 8 rows x 4 cols
__global__ __launch_bounds__(256) void atom_linear(const int* __restrict__ atom_z,
                                                   const float* __restrict__ table,
                                                   const float* __restrict__ w_f,
                                                   const float* __restrict__ w_c,
                                                   float* __restrict__ a_fc) {
    __shared__ float z[TL][H];
    __shared__ int zz[TL];
    int m0 = blockIdx.x * TL;
    int tid = threadIdx.x;
    if (tid < TL) {
        int gm = m0 + tid;
        zz[tid] = (gm < N_ATOMS) ? atom_z[gm] : 0;
    }
    __syncthreads();
    for (int idx = tid; idx < TL * 16; idx += 256) {
        int m = idx >> 4, k4 = idx & 15;
        float4 v = ((const float4*)table)[(size_t)zz[m] * 16 + k4];
        *(float4*)&z[m][k4 * 4] = v;
    }
    __syncthreads();
    int rg = tid >> 5;          // 8 row groups of 8
    int cg = tid & 31;          // 32 col groups of 4 (128 outputs: f then c)
    int c0 = cg * 4;
    int sel = (c0 >= 64) ? 1 : 0;
    int jj = c0 & 63;
    const float* wsrc = (sel ? w_c : w_f) + jj;
    float acc[8][4];
#pragma unroll
    for (int i = 0; i < 8; i++)
#pragma unroll
        for (int c = 0; c < 4; c++) acc[i][c] = 0.0f;
    for (int k = 0; k < H; k += 2) {
        float4 w0 = *(const float4*)(wsrc + (size_t)k * H);
        float4 w1 = *(const float4*)(wsrc + (size_t)(k + 1) * H);
        float2 zv[8];
#pragma unroll
        for (int i = 0; i < 8; i++) zv[i] = *(const float2*)&z[rg * 8 + i][k];
#pragma unroll
        for (int i = 0; i < 8; i++) {
            acc[i][0] += zv[i].x * w0.x + zv[i].y * w1.x;
            acc[i][1] += zv[i].x * w0.y + zv[i].y * w1.y;
            acc[i][2] += zv[i].x * w0.z + zv[i].y * w1.z;
            acc[i][3] += zv[i].x * w0.w + zv[i].y * w1.w;
        }
    }
#pragma unroll
    for (int i = 0; i < 8; i++) {
        int gm = m0 + rg * 8 + i;
        if (gm < N_ATOMS) {
#pragma unroll
            for (int c = 0; c < 4; c++)
                a_fc[(((size_t)gm * H + (jj + c)) << 1) + sel] = acc[i][c];
        }
    }
}

// hx_mean from LDS-resident embed table; CSR motif side holds atom types
#define MPB 16
__global__ __launch_bounds__(256) void hx_gather(const unsigned* __restrict__ base,
                                                 const unsigned* __restrict__ cnt,
                                                 const int* __restrict__ csr_val,
                                                 const float* __restrict__ table,
                                                 float* __restrict__ hx_mean) {
    __shared__ float tab[NZ * H];
    int tid = threadIdx.x;
    for (int idx = tid; idx < NZ * H; idx += 256) tab[idx] = table[idx];
    __syncthreads();
    int wave = tid >> 6, j = tid & 63;
    for (int w = 0; w < MPB / 4; w++) {
        int m = blockIdx.x * MPB + wave * (MPB / 4) + w;
        unsigned b = base[m];
        unsigned d = cnt[m];
        float acc = 0.0f;
        unsigned k = 0;
        for (; k + 4 <= d; k += 4) {
            int z0 = csr_val[b + k],     z1 = csr_val[b + k + 1];
            int z2 = csr_val[b + k + 2], z3 = csr_val[b + k + 3];
            acc += tab[z0 * H + j] + tab[z1 * H + j] + tab[z2 * H + j] + tab[z3 * H + j];
        }
        for (; k < d; k++) acc += tab[csr_val[b + k] * H + j];
        hx_mean[(size_t)m * H + j] = acc / fmaxf((float)d, 1.0f);
    }
}

// motif projection (K=158, rows 64:222 of w_f/w_c, +bias), register-blocked 8x4
__global__ __launch_bounds__(256) void motif_linear(const float* __restrict__ hx_mean,
                                                    const float* __restrict__ motif_attr,
                                                    const float* __restrict__ w_f,
                                                    const float* __restrict__ b_f,
                                                    const float* __restrict__ w_c,
                                                    const float* __restrict__ b_c,
                                                    float* __restrict__ m_fc) {
    __shared__ float z[TL][160];   // 158 used
    int m0 = blockIdx.x * TL;
    int tid = threadIdx.x;
    for (int idx = tid; idx < TL * 16; idx += 256) {
        int m = idx >> 4, k4 = idx & 15;
        int gm = m0 + m;
        float4 v = make_float4(0.f, 0.f, 0.f, 0.f);
        if (gm < N_MOTIFS) v = ((const float4*)hx_mean)[(size_t)gm * 16 + k4];
        *(float4*)&z[m][k4 * 4] = v;
    }
    for (int idx = tid; idx < TL * 47; idx += 256) {
        int m = idx / 47, k2 = idx % 47;
        int gm = m0 + m;
        float2 v = make_float2(0.f, 0.f);
        if (gm < N_MOTIFS) v = ((const float2*)motif_attr)[(size_t)gm * 47 + k2];
        *(float2*)&z[m][H + k2 * 2] = v;
    }
    __syncthreads();
    int rg = tid >> 5;
    int cg = tid & 31;
    int c0 = cg * 4;
    int sel = (c0 >= 64) ? 1 : 0;
    int jj = c0 & 63;
    const float* wsrc = (sel ? w_c : w_f) + (size_t)H * H + jj;
    float4 bias = *(const float4*)((sel ? b_c : b_f) + jj);
    float acc[8][4];
#pragma unroll
    for (int i = 0; i < 8; i++) {
        acc[i][0] = bias.x; acc[i][1] = bias.y; acc[i][2] = bias.z; acc[i][3] = bias.w;
    }
    for (int k = 0; k < H + MOTIF_DIM; k += 2) {
        float4 w0 = *(const float4*)(wsrc + (size_t)k * H);
        float4 w1 = *(const float4*)(wsrc + (size_t)(k + 1) * H);
        float2 zv[8];
#pragma unroll
        for (int i = 0; i < 8; i++) zv[i] = *(const float2*)&z[rg * 8 + i][k];
#pragma unroll
        for (int i = 0; i < 8; i++) {
            acc[i][0] += zv[i].x * w0.x + zv[i].y * w1.x;
            acc[i][1] += zv[i].x * w0.y + zv[i].y * w1.y;
            acc[i][2] += zv[i].x * w0.z + zv[i].y * w1.z;
            acc[i][3] += zv[i].x * w0.w + zv[i].y * w1.w;
        }
    }
#pragma unroll
    for (int i = 0; i < 8; i++) {
        int gm = m0 + rg * 8 + i;
        if (gm < N_MOTIFS) {
#pragma unroll
            for (int c = 0; c < 4; c++)
                m_fc[(((size_t)gm * H + (jj + c)) << 1) + sel] = acc[i][c];
        }
    }
}

// one wave per atom: out_mean[i] = mean_h gate(a_fc[i] + m_fc[h]); 8-deep MLP
__global__ __launch_bounds__(256) void msg_gather(const unsigned* __restrict__ base,
                                                  const unsigned* __restrict__ cnt,
                                                  const int* __restrict__ csr_val,
                                                  const float2* __restrict__ a_fc,
                                                  const float2* __restrict__ m_fc,
                                                  float* __restrict__ out_mean) {
    int i = blockIdx.x * 4 + (threadIdx.x >> 6);
    int j = threadIdx.x & 63;
    float2 a = a_fc[(size_t)i * H + j];
    unsigned b = base[N_MOTIFS + i];
    unsigned d = cnt[N_MOTIFS + i];
    float acc = 0.0f;
    unsigned k = 0;
    for (; k + 8 <= d; k += 8) {
        int hh[8];
#pragma unroll
        for (int u = 0; u < 8; u++) hh[u] = csr_val[b + k + u];
        float2 v[8];
#pragma unroll
        for (int u = 0; u < 8; u++) v[u] = m_fc[(size_t)hh[u] * H + j];
#pragma unroll
        for (int u = 0; u < 8; u++) acc += gate_f(a.x + v[u].x, a.y + v[u].y);
    }
    for (; k + 2 <= d; k += 2) {
        int h0 = csr_val[b + k], h1 = csr_val[b + k + 1];
        float2 v0 = m_fc[(size_t)h0 * H + j];
        float2 v1 = m_fc[(size_t)h1 * H + j];
        acc += gate_f(a.x + v0.x, a.y + v0.y) + gate_f(a.x + v1.x, a.y + v1.y);
    }
    for (; k < d; k++) {
        int h0 = csr_val[b + k];
        float2 v0 = m_fc[(size_t)h0 * H + j];
        acc += gate_f(a.x + v0.x, a.y + v0.y);
    }
    out_mean[(size_t)i * H + j] = acc / fmaxf((float)d, 1.0f);
}

// column-wise sum and sumsq of out_mean over atoms
__global__ __launch_bounds__(256) void bn_stats(const float* __restrict__ out_mean,
                                                float* __restrict__ bn_sum,
                                                float* __restrict__ bn_sq) {
    __shared__ float ssum[256];
    __shared__ float ssq[256];
    int j = threadIdx.x & 63;
    int row = threadIdx.x >> 6;
    float s = 0.0f, q = 0.0f;
    for (int i = blockIdx.x * 4 + row; i < N_ATOMS; i += gridDim.x * 4) {
        float v = out_mean[(size_t)i * H + j];
        s += v; q += v * v;
    }
    ssum[threadIdx.x] = s; ssq[threadIdx.x] = q;
    __syncthreads();
    if (threadIdx.x < 64) {
        float ts = ssum[j] + ssum[64 + j] + ssum[128 + j] + ssum[192 + j];
        float tq = ssq[j] + ssq[64 + j] + ssq[128 + j] + ssq[192 + j];
        atomicAdd(&bn_sum[j], ts);
        atomicAdd(&bn_sq[j], tq);
    }
}

// 513 binary searches: gstart[g] = first atom with batch >= g (batch is sorted)
__global__ __launch_bounds__(256) void graph_bounds(const int* __restrict__ batch,
                                                    int* __restrict__ gstart) {
    int g = blockIdx.x * 256 + threadIdx.x;
    if (g > N_GRAPHS) return;
    int lo = 0, hi = N_ATOMS;
    while (lo < hi) {
        int mid = (lo + hi) >> 1;
        if (batch[mid] < g) lo = mid + 1; else hi = mid;
    }
    gstart[g] = lo;
}

// one block per graph: fused BN-apply + residual(from table) + relu + mean-pool. No atomics.
__global__ __launch_bounds__(256) void pool_kernel(const float* __restrict__ out_mean,
                                                   const float* __restrict__ bn_sum,
                                                   const float* __restrict__ bn_sq,
                                                   const float* __restrict__ gamma,
                                                   const float* __restrict__ beta,
                                                   const int* __restrict__ atom_z,
                                                   const float* __restrict__ table,
                                                   const int* __restrict__ gstart,
                                                   float* __restrict__ g_mean) {
    int g = blockIdx.x;
    int s = gstart[g], e = gstart[g + 1];
    int j = threadIdx.x & 63, w = threadIdx.x >> 6;
    const float invN = 1.0f / (float)N_ATOMS;
    float mu = bn_sum[j] * invN;
    float var = bn_sq[j] * invN - mu * mu;
    float rstd = 1.0f / sqrtf(var + BN_EPS);
    float gm = gamma[j], bt = beta[j];
    float acc = 0.0f;
    for (int i = s + w; i < e; i += 4) {
        float d = out_mean[(size_t)i * H + j];
        float xv = table[(size_t)atom_z[i] * H + j];   // recompute embed (101 hot rows)
        float o = (d - mu) * rstd * gm + bt;
        acc += fmaxf(o + xv, 0.0f);
    }
    __shared__ float red[256];
    red[threadIdx.x] = acc;
    __syncthreads();
    if (threadIdx.x < 64) {
        float t = red[j] + red[64 + j] + red[128 + j] + red[192 + j];
        g_mean[(size_t)g * H + j] = t / fmaxf((float)(e - s), 1.0f);
    }
}

// per-graph MLP head (g_mean already normalized)
__global__ __launch_bounds__(128) void head_kernel(const float* __restrict__ g_mean,
                                                   const float* __restrict__ w_l1,
                                                   const float* __restrict__ b_l1,
                                                   const float* __restrict__ w_out,
                                                   const float* __restrict__ b_out,
                                                   float* __restrict__ out) {
    __shared__ float gv[H];
    __shared__ float red[HOUT];
    int g = blockIdx.x, t = threadIdx.x;
    if (t < H) gv[t] = g_mean[(size_t)g * H + t];
    __syncthreads();
    float acc = b_l1[t];
    for (int k = 0; k < H; k++) acc += gv[k] * w_l1[(size_t)k * HOUT + t];
    float h = softplus_fast(acc);
    red[t] = h * w_out[t];
    __syncthreads();
    for (int s = 64; s > 0; s >>= 1) {
        if (t < s) red[t] += red[t + s];
        __syncthreads();
    }
    if (t == 0) out[g] = red[0] + b_out[0];
}

extern "C" void kernel_launch(void* const* d_in, const int* in_sizes, int n_in,
                              void* d_out, int out_size, void* d_ws, size_t ws_size,
                              hipStream_t stream) {
    const int*   atom_z     = (const int*)  d_in[0];
    const float* motif_attr = (const float*)d_in[1];
    const int*   he         = (const int*)  d_in[2];
    const int*   batch      = (const int*)  d_in[3];
    const float* table      = (const float*)d_in[4];
    const float* w_f        = (const float*)d_in[5];
    const float* b_f        = (const float*)d_in[6];
    const float* w_c        = (const float*)d_in[7];
    const float* b_c        = (const float*)d_in[8];
    const float* gamma      = (const float*)d_in[9];
    const float* beta       = (const float*)d_in[10];
    const float* w_l1       = (const float*)d_in[11];
    const float* b_l1       = (const float*)d_in[12];
    const float* w_out      = (const float*)d_in[13];
    const float* b_out      = (const float*)d_in[14];
    float* out = (float*)d_out;

    // ---- workspace layout ----
    // zeroed region: cnt + bn accumulators only
    unsigned* cnt    = (unsigned*)d_ws;                    // 100,000
    float*    bn_sum = (float*)(cnt + N_SEG);              // 64
    float*    bn_sq  = bn_sum + H;                         // 64
    char*     zero_end = (char*)(bn_sq + H);
    // un-zeroed region:
    unsigned* base     = (unsigned*)zero_end;              // 100,000
    unsigned* cur      = base + N_SEG;                     // 100,000
    unsigned* part     = cur + N_SEG;                      // 128
    unsigned* part_pre = part + 128;                       // 128
    int*      gstart   = (int*)(part_pre + 128);           // 513 (+pad)
    int*      csr_val  = gstart + 516;                     // 1,200,000
    float*    a_fc     = (float*)(csr_val + 2 * N_INC);    // 6.4M interleaved
    float*    m_fc     = a_fc + (size_t)N_ATOMS * H * 2;   // 6.4M interleaved
    float*    hx_mean  = m_fc + (size_t)N_MOTIFS * H * 2;  // 3.2M
    float*    out_mean = hx_mean;                          // alias (hx dead after motif_linear)
    float*    g_mean   = out_mean + (size_t)N_ATOMS * H;   // 32,768

    size_t zero_bytes = (size_t)(zero_end - (char*)d_ws);
    hipMemsetAsync(d_ws, 0, zero_bytes, stream);

    count_kernel<<<(N_INC + 255) / 256, 256, 0, stream>>>(he, cnt);
    scan_part<<<SCAN_NBLK, 256, 0, stream>>>(cnt, part);
    scan_top<<<1, 128, 0, stream>>>(part, part_pre);
    scan_down<<<SCAN_NBLK, 256, 0, stream>>>(cnt, part_pre, base, cur);
    fill_kernel<<<512, 256, 0, stream>>>(he, atom_z, cur, csr_val);
    graph_bounds<<<3, 256, 0, stream>>>(batch, gstart);
    atom_linear<<<NBLK_L, 256, 0, stream>>>(atom_z, table, w_f, w_c, a_fc);
    hx_gather<<<N_MOTIFS / MPB, 256, 0, stream>>>(base, cnt, csr_val, table, hx_mean);
    motif_linear<<<NBLK_L, 256, 0, stream>>>(hx_mean, motif_attr,
                                             w_f, b_f, w_c, b_c, m_fc);
    msg_gather<<<N_ATOMS / 4, 256, 0, stream>>>(base, cnt, csr_val,
                                                (const float2*)a_fc, (const float2*)m_fc,
                                                out_mean);
    bn_stats<<<1024, 256, 0, stream>>>(out_mean, bn_sum, bn_sq);
    pool_kernel<<<N_GRAPHS, 256, 0, stream>>>(out_mean, bn_sum, bn_sq, gamma, beta,
                                              atom_z, table, gstart, g_mean);
    head_kernel<<<N_GRAPHS, 128, 0, stream>>>(g_mean, w_l1, b_l1, w_out, b_out, out);
}

// Round 6
// 412.284 us; speedup vs baseline: 1.7713x; 1.0299x over previous
//
#include <hip/hip_runtime.h>
#include <hip/hip_bf16.h>
#include <math.h>

#define N_ATOMS  50000
#define N_MOTIFS 50000
#define N_SEG    (N_MOTIFS + N_ATOMS)   // 100000 combined segments
#define N_INC    600000
#define N_GRAPHS 512
#define H        64
#define MOTIF_DIM 94
#define HOUT     128
#define BN_EPS   1e-5f
#define NZ       101
#define SCAN_NBLK 98                    // ceil(100000/1024)
#define TL       64                     // rows per block in the linear kernels
#define NBLK_L   ((N_ATOMS + TL - 1) / TL)   // 782

__device__ __forceinline__ float softplus_fast(float x) {
    return fmaxf(x, 0.0f) + __logf(1.0f + __expf(-fabsf(x)));
}
__device__ __forceinline__ float gate_f(float f, float c) {
    float sig = __builtin_amdgcn_rcpf(1.0f + __expf(-f));
    return sig * softplus_fast(c);
}

// degree histogram over combined segment space: [0,50k)=motifs, [50k,100k)=atoms
__global__ __launch_bounds__(256) void count_kernel(const int* __restrict__ he,
                                                    unsigned* __restrict__ cnt) {
    int e = blockIdx.x * 256 + threadIdx.x;
    if (e >= N_INC) return;
    atomicAdd(&cnt[he[N_INC + e]], 1u);
    atomicAdd(&cnt[N_MOTIFS + he[e]], 1u);
}

// phase 1: per-block (1024 elems) sums
__global__ __launch_bounds__(256) void scan_part(const unsigned* __restrict__ cnt,
                                                 unsigned* __restrict__ part) {
    __shared__ unsigned red[256];
    int b = blockIdx.x, t = threadIdx.x;
    int i0 = b * 1024 + t * 4;
    unsigned s = 0;
#pragma unroll
    for (int i = 0; i < 4; i++) { int idx = i0 + i; if (idx < N_SEG) s += cnt[idx]; }
    red[t] = s;
    __syncthreads();
    for (int off = 128; off > 0; off >>= 1) {
        if (t < off) red[t] += red[t + off];
        __syncthreads();
    }
    if (t == 0) part[b] = red[0];
}

// phase 2: exclusive scan of 98 block sums
__global__ __launch_bounds__(128) void scan_top(const unsigned* __restrict__ part,
                                                unsigned* __restrict__ part_pre) {
    __shared__ unsigned s[128];
    int t = threadIdx.x;
    s[t] = (t < SCAN_NBLK) ? part[t] : 0u;
    __syncthreads();
    for (int off = 1; off < 128; off <<= 1) {
        unsigned add = (t >= off) ? s[t - off] : 0u;
        __syncthreads();
        s[t] += add;
        __syncthreads();
    }
    if (t < SCAN_NBLK) part_pre[t] = (t > 0) ? s[t - 1] : 0u;
}

// phase 3: block-local exclusive scan + global offset -> base, cur
__global__ __launch_bounds__(256) void scan_down(const unsigned* __restrict__ cnt,
                                                 const unsigned* __restrict__ part_pre,
                                                 unsigned* __restrict__ base,
                                                 unsigned* __restrict__ cur) {
    __shared__ unsigned s[256];
    int b = blockIdx.x, t = threadIdx.x;
    int i0 = b * 1024 + t * 4;
    unsigned c[4];
#pragma unroll
    for (int i = 0; i < 4; i++) { int idx = i0 + i; c[i] = (idx < N_SEG) ? cnt[idx] : 0u; }
    s[t] = c[0] + c[1] + c[2] + c[3];
    __syncthreads();
    for (int off = 1; off < 256; off <<= 1) {
        unsigned add = (t >= off) ? s[t - off] : 0u;
        __syncthreads();
        s[t] += add;
        __syncthreads();
    }
    unsigned pre = part_pre[b] + ((t > 0) ? s[t - 1] : 0u);
#pragma unroll
    for (int i = 0; i < 4; i++) {
        int idx = i0 + i;
        if (idx < N_SEG) { base[idx] = pre; cur[idx] = pre; pre += c[i]; }
    }
}

// XCD-partitioned CSR fill (class = blockIdx%8 -> XCD; writes only its segment groups)
__global__ __launch_bounds__(256) void fill_kernel(const int* __restrict__ he,
                                                   const int* __restrict__ atom_z,
                                                   unsigned* __restrict__ cur,
                                                   int* __restrict__ csr_val) {
    int cls = blockIdx.x & 7;
    int bi  = blockIdx.x >> 3;
    int nb  = gridDim.x >> 3;
    for (int e = bi * 256 + threadIdx.x; e < N_INC; e += nb * 256) {
        int s = he[e];
        int h = he[N_INC + e];
        if (((h >> 4) & 7) == cls) {
            unsigned p = atomicAdd(&cur[h], 1u);
            csr_val[p] = atom_z[s];
        }
        if (((s >> 4) & 7) == cls) {
            unsigned q = atomicAdd(&cur[N_MOTIFS + s], 1u);
            csr_val[q] = h;
        }
    }
}

// embed (LDS-staged table rows) + atom projection; 8 rows x 4 cols/thread,
// k-step 4 with one-iteration-ahead register prefetch of the w rows.
__global__ __launch_bounds__(256) void atom_linear(const int* __restrict__ atom_z,
                                                   const float* __restrict__ table,
                                                   const float* __restrict__ w_f,
                                                   const float* __restrict__ w_c,
                                                   float* __restrict__ a_fc) {
    __shared__ float z[TL][H];
    __shared__ int zz[TL];
    int m0 = blockIdx.x * TL;
    int tid = threadIdx.x;
    if (tid < TL) {
        int gm = m0 + tid;
        zz[tid] = (gm < N_ATOMS) ? atom_z[gm] : 0;
    }
    __syncthreads();
    for (int idx = tid; idx < TL * 16; idx += 256) {
        int m = idx >> 4, k4 = idx & 15;
        float4 v = ((const float4*)table)[(size_t)zz[m] * 16 + k4];
        *(float4*)&z[m][k4 * 4] = v;
    }
    __syncthreads();
    int rg = tid >> 5;          // 8 row groups of 8
    int cg = tid & 31;          // 32 col groups of 4 (128 outputs: f then c)
    int c0 = cg * 4;
    int sel = (c0 >= 64) ? 1 : 0;
    int jj = c0 & 63;
    const float* wsrc = (sel ? w_c : w_f) + jj;
    float acc[8][4];
#pragma unroll
    for (int i = 0; i < 8; i++)
#pragma unroll
        for (int c = 0; c < 4; c++) acc[i][c] = 0.0f;
    float4 wb0 = *(const float4*)(wsrc);
    float4 wb1 = *(const float4*)(wsrc + H);
    float4 wb2 = *(const float4*)(wsrc + 2 * H);
    float4 wb3 = *(const float4*)(wsrc + 3 * H);
    for (int k = 0; k < H - 4; k += 4) {
        float4 nw0 = *(const float4*)(wsrc + (size_t)(k + 4) * H);
        float4 nw1 = *(const float4*)(wsrc + (size_t)(k + 5) * H);
        float4 nw2 = *(const float4*)(wsrc + (size_t)(k + 6) * H);
        float4 nw3 = *(const float4*)(wsrc + (size_t)(k + 7) * H);
        float4 zv[8];
#pragma unroll
        for (int i = 0; i < 8; i++) zv[i] = *(const float4*)&z[rg * 8 + i][k];
#pragma unroll
        for (int i = 0; i < 8; i++) {
            acc[i][0] += zv[i].x * wb0.x + zv[i].y * wb1.x + zv[i].z * wb2.x + zv[i].w * wb3.x;
            acc[i][1] += zv[i].x * wb0.y + zv[i].y * wb1.y + zv[i].z * wb2.y + zv[i].w * wb3.y;
            acc[i][2] += zv[i].x * wb0.z + zv[i].y * wb1.z + zv[i].z * wb2.z + zv[i].w * wb3.z;
            acc[i][3] += zv[i].x * wb0.w + zv[i].y * wb1.w + zv[i].z * wb2.w + zv[i].w * wb3.w;
        }
        wb0 = nw0; wb1 = nw1; wb2 = nw2; wb3 = nw3;
    }
    {   // tail k = 60..63 already in wb
        float4 zv[8];
#pragma unroll
        for (int i = 0; i < 8; i++) zv[i] = *(const float4*)&z[rg * 8 + i][H - 4];
#pragma unroll
        for (int i = 0; i < 8; i++) {
            acc[i][0] += zv[i].x * wb0.x + zv[i].y * wb1.x + zv[i].z * wb2.x + zv[i].w * wb3.x;
            acc[i][1] += zv[i].x * wb0.y + zv[i].y * wb1.y + zv[i].z * wb2.y + zv[i].w * wb3.y;
            acc[i][2] += zv[i].x * wb0.z + zv[i].y * wb1.z + zv[i].z * wb2.z + zv[i].w * wb3.z;
            acc[i][3] += zv[i].x * wb0.w + zv[i].y * wb1.w + zv[i].z * wb2.w + zv[i].w * wb3.w;
        }
    }
#pragma unroll
    for (int i = 0; i < 8; i++) {
        int gm = m0 + rg * 8 + i;
        if (gm < N_ATOMS) {
#pragma unroll
            for (int c = 0; c < 4; c++)
                a_fc[(((size_t)gm * H + (jj + c)) << 1) + sel] = acc[i][c];
        }
    }
}

// hx_mean from LDS-resident embed table; CSR motif side holds atom types
#define MPB 16
__global__ __launch_bounds__(256) void hx_gather(const unsigned* __restrict__ base,
                                                 const unsigned* __restrict__ cnt,
                                                 const int* __restrict__ csr_val,
                                                 const float* __restrict__ table,
                                                 float* __restrict__ hx_mean) {
    __shared__ float tab[NZ * H];
    int tid = threadIdx.x;
    for (int idx = tid; idx < NZ * H; idx += 256) tab[idx] = table[idx];
    __syncthreads();
    int wave = tid >> 6, j = tid & 63;
    for (int w = 0; w < MPB / 4; w++) {
        int m = blockIdx.x * MPB + wave * (MPB / 4) + w;
        unsigned b = base[m];
        unsigned d = cnt[m];
        float acc = 0.0f;
        unsigned k = 0;
        for (; k + 4 <= d; k += 4) {
            int z0 = csr_val[b + k],     z1 = csr_val[b + k + 1];
            int z2 = csr_val[b + k + 2], z3 = csr_val[b + k + 3];
            acc += tab[z0 * H + j] + tab[z1 * H + j] + tab[z2 * H + j] + tab[z3 * H + j];
        }
        for (; k < d; k++) acc += tab[csr_val[b + k] * H + j];
        hx_mean[(size_t)m * H + j] = acc / fmaxf((float)d, 1.0f);
    }
}

// motif projection (K=158, rows 64:222 of w_f/w_c, +bias); 8x4 register block,
// k-step 4 with one-iteration-ahead register prefetch of the w rows.
__global__ __launch_bounds__(256) void motif_linear(const float* __restrict__ hx_mean,
                                                    const float* __restrict__ motif_attr,
                                                    const float* __restrict__ w_f,
                                                    const float* __restrict__ b_f,
                                                    const float* __restrict__ w_c,
                                                    const float* __restrict__ b_c,
                                                    float* __restrict__ m_fc) {
    __shared__ float z[TL][160];   // 158 used
    int m0 = blockIdx.x * TL;
    int tid = threadIdx.x;
    for (int idx = tid; idx < TL * 16; idx += 256) {
        int m = idx >> 4, k4 = idx & 15;
        int gm = m0 + m;
        float4 v = make_float4(0.f, 0.f, 0.f, 0.f);
        if (gm < N_MOTIFS) v = ((const float4*)hx_mean)[(size_t)gm * 16 + k4];
        *(float4*)&z[m][k4 * 4] = v;
    }
    for (int idx = tid; idx < TL * 47; idx += 256) {
        int m = idx / 47, k2 = idx % 47;
        int gm = m0 + m;
        float2 v = make_float2(0.f, 0.f);
        if (gm < N_MOTIFS) v = ((const float2*)motif_attr)[(size_t)gm * 47 + k2];
        *(float2*)&z[m][H + k2 * 2] = v;
    }
    __syncthreads();
    int rg = tid >> 5;
    int cg = tid & 31;
    int c0 = cg * 4;
    int sel = (c0 >= 64) ? 1 : 0;
    int jj = c0 & 63;
    const float* wsrc = (sel ? w_c : w_f) + (size_t)H * H + jj;
    float4 bias = *(const float4*)((sel ? b_c : b_f) + jj);
    float acc[8][4];
#pragma unroll
    for (int i = 0; i < 8; i++) {
        acc[i][0] = bias.x; acc[i][1] = bias.y; acc[i][2] = bias.z; acc[i][3] = bias.w;
    }
    float4 wb0 = *(const float4*)(wsrc);
    float4 wb1 = *(const float4*)(wsrc + H);
    float4 wb2 = *(const float4*)(wsrc + 2 * H);
    float4 wb3 = *(const float4*)(wsrc + 3 * H);
    // K=158: main loop covers k=0..151 (38 iters), wb ends holding k=152..155
    for (int k = 0; k < 152; k += 4) {
        float4 nw0 = *(const float4*)(wsrc + (size_t)(k + 4) * H);
        float4 nw1 = *(const float4*)(wsrc + (size_t)(k + 5) * H);
        float4 nw2 = *(const float4*)(wsrc + (size_t)(k + 6) * H);
        float4 nw3 = *(const float4*)(wsrc + (size_t)(k + 7) * H);
        float4 zv[8];
#pragma unroll
        for (int i = 0; i < 8; i++) zv[i] = *(const float4*)&z[rg * 8 + i][k];
#pragma unroll
        for (int i = 0; i < 8; i++) {
            acc[i][0] += zv[i].x * wb0.x + zv[i].y * wb1.x + zv[i].z * wb2.x + zv[i].w * wb3.x;
            acc[i][1] += zv[i].x * wb0.y + zv[i].y * wb1.y + zv[i].z * wb2.y + zv[i].w * wb3.y;
            acc[i][2] += zv[i].x * wb0.z + zv[i].y * wb1.z + zv[i].z * wb2.z + zv[i].w * wb3.z;
            acc[i][3] += zv[i].x * wb0.w + zv[i].y * wb1.w + zv[i].z * wb2.w + zv[i].w * wb3.w;
        }
        wb0 = nw0; wb1 = nw1; wb2 = nw2; wb3 = nw3;
    }
    {   // tail k = 152..155 from wb
        float4 zv[8];
#pragma unroll
        for (int i = 0; i < 8; i++) zv[i] = *(const float4*)&z[rg * 8 + i][152];
#pragma unroll
        for (int i = 0; i < 8; i++) {
            acc[i][0] += zv[i].x * wb0.x + zv[i].y * wb1.x + zv[i].z * wb2.x + zv[i].w * wb3.x;
            acc[i][1] += zv[i].x * wb0.y + zv[i].y * wb1.y + zv[i].z * wb2.y + zv[i].w * wb3.y;
            acc[i][2] += zv[i].x * wb0.z + zv[i].y * wb1.z + zv[i].z * wb2.z + zv[i].w * wb3.z;
            acc[i][3] += zv[i].x * wb0.w + zv[i].y * wb1.w + zv[i].z * wb2.w + zv[i].w * wb3.w;
        }
    }
    {   // tail k = 156,157
        float4 w0 = *(const float4*)(wsrc + (size_t)156 * H);
        float4 w1 = *(const float4*)(wsrc + (size_t)157 * H);
        float2 zv[8];
#pragma unroll
        for (int i = 0; i < 8; i++) zv[i] = *(const float2*)&z[rg * 8 + i][156];
#pragma unroll
        for (int i = 0; i < 8; i++) {
            acc[i][0] += zv[i].x * w0.x + zv[i].y * w1.x;
            acc[i][1] += zv[i].x * w0.y + zv[i].y * w1.y;
            acc[i][2] += zv[i].x * w0.z + zv[i].y * w1.z;
            acc[i][3] += zv[i].x * w0.w + zv[i].y * w1.w;
        }
    }
#pragma unroll
    for (int i = 0; i < 8; i++) {
        int gm = m0 + rg * 8 + i;
        if (gm < N_MOTIFS) {
#pragma unroll
            for (int c = 0; c < 4; c++)
                m_fc[(((size_t)gm * H + (jj + c)) << 1) + sel] = acc[i][c];
        }
    }
}

// one wave per atom: out_mean[i] = mean_h gate(a_fc[i] + m_fc[h]); 8-deep MLP
__global__ __launch_bounds__(256) void msg_gather(const unsigned* __restrict__ base,
                                                  const unsigned* __restrict__ cnt,
                                                  const int* __restrict__ csr_val,
                                                  const float2* __restrict__ a_fc,
                                                  const float2* __restrict__ m_fc,
                                                  float* __restrict__ out_mean) {
    int i = blockIdx.x * 4 + (threadIdx.x >> 6);
    int j = threadIdx.x & 63;
    float2 a = a_fc[(size_t)i * H + j];
    unsigned b = base[N_MOTIFS + i];
    unsigned d = cnt[N_MOTIFS + i];
    float acc = 0.0f;
    unsigned k = 0;
    for (; k + 8 <= d; k += 8) {
        int hh[8];
#pragma unroll
        for (int u = 0; u < 8; u++) hh[u] = csr_val[b + k + u];
        float2 v[8];
#pragma unroll
        for (int u = 0; u < 8; u++) v[u] = m_fc[(size_t)hh[u] * H + j];
#pragma unroll
        for (int u = 0; u < 8; u++) acc += gate_f(a.x + v[u].x, a.y + v[u].y);
    }
    for (; k + 2 <= d; k += 2) {
        int h0 = csr_val[b + k], h1 = csr_val[b + k + 1];
        float2 v0 = m_fc[(size_t)h0 * H + j];
        float2 v1 = m_fc[(size_t)h1 * H + j];
        acc += gate_f(a.x + v0.x, a.y + v0.y) + gate_f(a.x + v1.x, a.y + v1.y);
    }
    for (; k < d; k++) {
        int h0 = csr_val[b + k];
        float2 v0 = m_fc[(size_t)h0 * H + j];
        acc += gate_f(a.x + v0.x, a.y + v0.y);
    }
    out_mean[(size_t)i * H + j] = acc / fmaxf((float)d, 1.0f);
}

// column-wise sum and sumsq of out_mean over atoms
__global__ __launch_bounds__(256) void bn_stats(const float* __restrict__ out_mean,
                                                float* __restrict__ bn_sum,
                                                float* __restrict__ bn_sq) {
    __shared__ float ssum[256];
    __shared__ float ssq[256];
    int j = threadIdx.x & 63;
    int row = threadIdx.x >> 6;
    float s = 0.0f, q = 0.0f;
    for (int i = blockIdx.x * 4 + row; i < N_ATOMS; i += gridDim.x * 4) {
        float v = out_mean[(size_t)i * H + j];
        s += v; q += v * v;
    }
    ssum[threadIdx.x] = s; ssq[threadIdx.x] = q;
    __syncthreads();
    if (threadIdx.x < 64) {
        float ts = ssum[j] + ssum[64 + j] + ssum[128 + j] + ssum[192 + j];
        float tq = ssq[j] + ssq[64 + j] + ssq[128 + j] + ssq[192 + j];
        atomicAdd(&bn_sum[j], ts);
        atomicAdd(&bn_sq[j], tq);
    }
}

// 513 binary searches: gstart[g] = first atom with batch >= g (batch is sorted)
__global__ __launch_bounds__(256) void graph_bounds(const int* __restrict__ batch,
                                                    int* __restrict__ gstart) {
    int g = blockIdx.x * 256 + threadIdx.x;
    if (g > N_GRAPHS) return;
    int lo = 0, hi = N_ATOMS;
    while (lo < hi) {
        int mid = (lo + hi) >> 1;
        if (batch[mid] < g) lo = mid + 1; else hi = mid;
    }
    gstart[g] = lo;
}

// one block per graph: fused BN-apply + residual(from table) + relu + mean-pool. No atomics.
__global__ __launch_bounds__(256) void pool_kernel(const float* __restrict__ out_mean,
                                                   const float* __restrict__ bn_sum,
                                                   const float* __restrict__ bn_sq,
                                                   const float* __restrict__ gamma,
                                                   const float* __restrict__ beta,
                                                   const int* __restrict__ atom_z,
                                                   const float* __restrict__ table,
                                                   const int* __restrict__ gstart,
                                                   float* __restrict__ g_mean) {
    int g = blockIdx.x;
    int s = gstart[g], e = gstart[g + 1];
    int j = threadIdx.x & 63, w = threadIdx.x >> 6;
    const float invN = 1.0f / (float)N_ATOMS;
    float mu = bn_sum[j] * invN;
    float var = bn_sq[j] * invN - mu * mu;
    float rstd = 1.0f / sqrtf(var + BN_EPS);
    float gm = gamma[j], bt = beta[j];
    float acc = 0.0f;
    for (int i = s + w; i < e; i += 4) {
        float d = out_mean[(size_t)i * H + j];
        float xv = table[(size_t)atom_z[i] * H + j];
        float o = (d - mu) * rstd * gm + bt;
        acc += fmaxf(o + xv, 0.0f);
    }
    __shared__ float red[256];
    red[threadIdx.x] = acc;
    __syncthreads();
    if (threadIdx.x < 64) {
        float t = red[j] + red[64 + j] + red[128 + j] + red[192 + j];
        g_mean[(size_t)g * H + j] = t / fmaxf((float)(e - s), 1.0f);
    }
}

// per-graph MLP head
__global__ __launch_bounds__(128) void head_kernel(const float* __restrict__ g_mean,
                                                   const float* __restrict__ w_l1,
                                                   const float* __restrict__ b_l1,
                                                   const float* __restrict__ w_out,
                                                   const float* __restrict__ b_out,
                                                   float* __restrict__ out) {
    __shared__ float gv[H];
    __shared__ float red[HOUT];
    int g = blockIdx.x, t = threadIdx.x;
    if (t < H) gv[t] = g_mean[(size_t)g * H + t];
    __syncthreads();
    float acc = b_l1[t];
    for (int k = 0; k < H; k++) acc += gv[k] * w_l1[(size_t)k * HOUT + t];
    float h = softplus_fast(acc);
    red[t] = h * w_out[t];
    __syncthreads();
    for (int s = 64; s > 0; s >>= 1) {
        if (t < s) red[t] += red[t + s];
        __syncthreads();
    }
    if (t == 0) out[g] = red[0] + b_out[0];
}

extern "C" void kernel_launch(void* const* d_in, const int* in_sizes, int n_in,
                              void* d_out, int out_size, void* d_ws, size_t ws_size,
                              hipStream_t stream) {
    const int*   atom_z     = (const int*)  d_in[0];
    const float* motif_attr = (const float*)d_in[1];
    const int*   he         = (const int*)  d_in[2];
    const int*   batch      = (const int*)  d_in[3];
    const float* table      = (const float*)d_in[4];
    const float* w_f        = (const float*)d_in[5];
    const float* b_f        = (const float*)d_in[6];
    const float* w_c        = (const float*)d_in[7];
    const float* b_c        = (const float*)d_in[8];
    const float* gamma      = (const float*)d_in[9];
    const float* beta       = (const float*)d_in[10];
    const float* w_l1       = (const float*)d_in[11];
    const float* b_l1       = (const float*)d_in[12];
    const float* w_out      = (const float*)d_in[13];
    const float* b_out      = (const float*)d_in[14];
    float* out = (float*)d_out;

    // ---- workspace layout ----
    unsigned* cnt    = (unsigned*)d_ws;                    // 100,000 (zeroed)
    float*    bn_sum = (float*)(cnt + N_SEG);              // 64
    float*    bn_sq  = bn_sum + H;                         // 64
    char*     zero_end = (char*)(bn_sq + H);
    unsigned* base     = (unsigned*)zero_end;              // 100,000
    unsigned* cur      = base + N_SEG;                     // 100,000
    unsigned* part     = cur + N_SEG;                      // 128
    unsigned* part_pre = part + 128;                       // 128
    int*      gstart   = (int*)(part_pre + 128);           // 513 (+pad)
    int*      csr_val  = gstart + 516;                     // 1,200,000
    float*    a_fc     = (float*)(csr_val + 2 * N_INC);    // 6.4M interleaved
    float*    m_fc     = a_fc + (size_t)N_ATOMS * H * 2;   // 6.4M interleaved
    float*    hx_mean  = m_fc + (size_t)N_MOTIFS * H * 2;  // 3.2M
    float*    out_mean = hx_mean;                          // alias (hx dead after motif_linear)
    float*    g_mean   = out_mean + (size_t)N_ATOMS * H;   // 32,768

    size_t zero_bytes = (size_t)(zero_end - (char*)d_ws);
    hipMemsetAsync(d_ws, 0, zero_bytes, stream);

    count_kernel<<<(N_INC + 255) / 256, 256, 0, stream>>>(he, cnt);
    scan_part<<<SCAN_NBLK, 256, 0, stream>>>(cnt, part);
    scan_top<<<1, 128, 0, stream>>>(part, part_pre);
    scan_down<<<SCAN_NBLK, 256, 0, stream>>>(cnt, part_pre, base, cur);
    fill_kernel<<<512, 256, 0, stream>>>(he, atom_z, cur, csr_val);
    graph_bounds<<<3, 256, 0, stream>>>(batch, gstart);
    atom_linear<<<NBLK_L, 256, 0, stream>>>(atom_z, table, w_f, w_c, a_fc);
    hx_gather<<<N_MOTIFS / MPB, 256, 0, stream>>>(base, cnt, csr_val, table, hx_mean);
    motif_linear<<<NBLK_L, 256, 0, stream>>>(hx_mean, motif_attr,
                                             w_f, b_f, w_c, b_c, m_fc);
    msg_gather<<<N_ATOMS / 4, 256, 0, stream>>>(base, cnt, csr_val,
                                                (const float2*)a_fc, (const float2*)m_fc,
                                                out_mean);
    bn_stats<<<1024, 256, 0, stream>>>(out_mean, bn_sum, bn_sq);
    pool_kernel<<<N_GRAPHS, 256, 0, stream>>>(out_mean, bn_sum, bn_sq, gamma, beta,
                                              atom_z, table, gstart, g_mean);
    head_kernel<<<N_GRAPHS, 128, 0, stream>>>(g_mean, w_l1, b_l1, w_out, b_out, out);
}